// Round 13
// baseline (3214.558 us; speedup 1.0000x reference)
//
#include <hip/hip_runtime.h>
#include <float.h>

#define B8 8
#define NPTS 4096

// ---------------- DPP helpers ----------------
template <int CTRL, int RM>
__device__ __forceinline__ unsigned dppmov(unsigned v) {
  return (unsigned)__builtin_amdgcn_update_dpp((int)v, (int)v, CTRL, RM, 0xf, false);
}

template <int CTRL, int RM>
__device__ __forceinline__ void red_key_max(unsigned& kh, unsigned& kl) {
  unsigned oh = dppmov<CTRL, RM>(kh);
  unsigned ol = dppmov<CTRL, RM>(kl);
  unsigned long long ko = ((unsigned long long)oh << 32) | ol;
  unsigned long long k  = ((unsigned long long)kh << 32) | kl;
  bool c = ko > k;
  kh = c ? oh : kh;
  kl = c ? ol : kl;
}

template <int CTRL, int RM>
__device__ __forceinline__ void red_key_min(unsigned& kh, unsigned& kl) {
  unsigned oh = dppmov<CTRL, RM>(kh);
  unsigned ol = dppmov<CTRL, RM>(kl);
  unsigned long long ko = ((unsigned long long)oh << 32) | ol;
  unsigned long long k  = ((unsigned long long)kh << 32) | kl;
  bool c = ko < k;
  kh = c ? oh : kh;
  kl = c ? ol : kl;
}

#define WAVE_RED_MAX(kh, kl)            \
  red_key_max<0x111, 0xf>(kh, kl);      \
  red_key_max<0x112, 0xf>(kh, kl);      \
  red_key_max<0x114, 0xf>(kh, kl);      \
  red_key_max<0x118, 0xf>(kh, kl);      \
  red_key_max<0x142, 0xa>(kh, kl);      \
  red_key_max<0x143, 0xc>(kh, kl);

#define WAVE_RED_MIN(kh, kl)            \
  red_key_min<0x111, 0xf>(kh, kl);      \
  red_key_min<0x112, 0xf>(kh, kl);      \
  red_key_min<0x114, 0xf>(kh, kl);      \
  red_key_min<0x118, 0xf>(kh, kl);      \
  red_key_min<0x142, 0xa>(kh, kl);      \
  red_key_min<0x143, 0xc>(kh, kl);

// ---------------- FPS + fused split (closed at ~324us) ----------------
template <int BLOCK, int P>
__global__ __launch_bounds__(BLOCK) void fps4_kernel(const float* __restrict__ x,
                                                     float* __restrict__ xyz,
                                                     float* __restrict__ nrm,
                                                     float4* __restrict__ xyz4,
                                                     int N, int S,
                                                     float* __restrict__ out_xyz) {
#pragma clang fp contract(off)
  constexpr int NW = BLOCK / 64;
  __shared__ float4 pts[BLOCK * P];
  __shared__ float4 sel[512];
  __shared__ alignas(16) unsigned long long wkey[2][NW];
  int b = blockIdx.x, t = threadIdx.x;
  const float* xb = x + (size_t)b * 6 * N;
  float px[P], py[P], pz[P], dist[P];
#pragma unroll
  for (int j = 0; j < P; ++j) {
    int idx = t + j * BLOCK;
    float a = xb[0 * N + idx], bb = xb[1 * N + idx], c = xb[2 * N + idx];
    px[j] = a; py[j] = bb; pz[j] = c;
    pts[idx] = make_float4(a, bb, c, 0.f);
    dist[j] = 1e10f;
    size_t g = (size_t)b * N + idx;
    float* o1 = xyz + g * 3;
    o1[0] = a; o1[1] = bb; o1[2] = c;
    xyz4[g] = make_float4(a, bb, c, a * a + bb * bb + c * c);
    float n0 = xb[3 * N + idx], n1 = xb[4 * N + idx], n2 = xb[5 * N + idx];
    float* o2 = nrm + g * 3;
    o2[0] = n0; o2[1] = n1; o2[2] = n2;
  }
  __syncthreads();
  float fx = xb[0], fy = xb[N], fz = xb[2 * N];
  for (int i = 0; i < S; ++i) {
    if (t == 0) sel[i] = make_float4(fx, fy, fz, 0.f);
    float bv = -1.0f;
    int bj = 0;
#pragma unroll
    for (int j = 0; j < P; ++j) {
      float dx = px[j] - fx, dy = py[j] - fy, dz = pz[j] - fz;
      float d = dx * dx + dy * dy + dz * dz;
      float nd = fminf(dist[j], d);
      dist[j] = nd;
      bool c = nd > bv;
      bv = c ? nd : bv;
      bj = c ? j : bj;
    }
    unsigned kh = __float_as_uint(bv);
    unsigned kl = (unsigned)(~(t + bj * BLOCK));
    WAVE_RED_MAX(kh, kl);
    int buf = i & 1;
    if ((t & 63) == 63)
      wkey[buf][t >> 6] = ((unsigned long long)kh << 32) | kl;
    __syncthreads();
    unsigned long long g = 0ull;
    const ulonglong2* wk2 = (const ulonglong2*)&wkey[buf][0];
#pragma unroll
    for (int w = 0; w < NW / 2; ++w) {
      ulonglong2 e = wk2[w];
      unsigned long long m = (e.x > e.y) ? e.x : e.y;
      g = (m > g) ? m : g;
    }
    int far = (int)~(unsigned)g;
    float4 f = pts[far];
    fx = f.x; fy = f.y; fz = f.z;
  }
  __syncthreads();
  for (int i = t; i < S; i += BLOCK) {
    float4 f = sel[i];
    float* o = out_xyz + ((size_t)b * S + i) * 3;
    o[0] = f.x; o[1] = f.y; o[2] = f.z;
  }
}

// ---------------- kNN k=20 + fused SA1 (R10 registerized) ----------------
__global__ __launch_bounds__(64) void knn20_kernel(const float* __restrict__ q,
                                                   const float4* __restrict__ ref4,
                                                   const float* __restrict__ nrm,
                                                   const float* __restrict__ W,
                                                   const float* __restrict__ bias,
                                                   float* __restrict__ f1) {
#pragma clang fp contract(off)
  int bs = blockIdx.x;                 // b*512 + s  (== group id)
  int b = bs >> 9;
  int t = threadIdx.x;
  __shared__ alignas(16) float smem_in[20][8];
  const float* qp = q + (size_t)bs * 3;
  float qx = qp[0], qy = qp[1], qz = qp[2];
  float qq = qx * qx + qy * qy + qz * qz;
  const float4* rp = ref4 + (size_t)b * 4096;
  float v1 = FLT_MAX, v2 = FLT_MAX;
  int i1 = 0, i2 = 0;
  for (int k = 0; k < 64; ++k) {
    int i = t + (k << 6);
    float4 r = rp[i];
    float dot = qx * r.x + qy * r.y + qz * r.z;
    float d = qq - 2.0f * dot + r.w;
    if (d < v1) { v2 = v1; i2 = i1; v1 = d; i1 = i; }
    else if (d < v2) { v2 = d; i2 = i; }
  }
  unsigned long long taken = 0ull;
  unsigned keep = 0;
  for (int k = 0; k < 20; ++k) {
    unsigned kh = __float_as_uint(v1), kl = (unsigned)i1;
    WAVE_RED_MIN(kh, kl);
    unsigned w = (unsigned)__builtin_amdgcn_readlane((int)kl, 63);
    if (t == k) keep = w;
    if (((int)w & 63) == t) {          // I owned the winner (w == my i1)
      taken |= 1ull << ((int)w >> 6);
      v1 = v2; i1 = i2;
      v2 = FLT_MAX; i2 = 0;
      if (v1 == FLT_MAX) {             // cache exhausted (rare): recompute scan
        for (int j = 0; j < 64; ++j) {
          if ((taken >> j) & 1ull) continue;
          int i = t + (j << 6);
          float4 r = rp[i];
          float dot = qx * r.x + qy * r.y + qz * r.z;
          float d = qq - 2.0f * dot + r.w;
          if (d < v1) { v2 = v1; i2 = i1; v1 = d; i1 = i; }
          else if (d < v2) { v2 = d; i2 = i; }
        }
      }
    }
  }
  if (t < 20) {
    int id = (int)keep;
    float4 r = rp[id];                 // (x,y,z,|p|^2)
    const float* nr = nrm + ((size_t)b * 4096 + id) * 3;
    smem_in[t][0] = r.x - qx;
    smem_in[t][1] = r.y - qy;
    smem_in[t][2] = r.z - qz;
    smem_in[t][3] = nr[0];
    smem_in[t][4] = nr[1];
    smem_in[t][5] = nr[2];
    smem_in[t][6] = 0.0f;
    smem_in[t][7] = 0.0f;
  }
  __syncthreads();
  float w0 = W[0 * 64 + t], w1 = W[1 * 64 + t], w2 = W[2 * 64 + t];
  float w3 = W[3 * 64 + t], w4 = W[4 * 64 + t], w5 = W[5 * 64 + t];
  float bb = bias[t];
  float m = 0.0f;                      // relu >= 0: 0-init absorbs the relu clamp
  for (int n = 0; n < 20; ++n) {
    const float4 a = *reinterpret_cast<const float4*>(&smem_in[n][0]);
    const float4 c = *reinterpret_cast<const float4*>(&smem_in[n][4]);
    float v = a.x * w0;
    v += a.y * w1;
    v += a.z * w2;
    v += a.w * w3;
    v += c.x * w4;
    v += c.y * w5;
    v += bb;
    m = fmaxf(m, v);
  }
  f1[(size_t)bs * 64 + t] = m;
}

// ---------------- knn3 select+store helper ----------------
__device__ __forceinline__ void knn3_store(int g, const float* rx3,
                                           float qx, float qy, float qz,
                                           int i0, int i1, int i2,
                                           int* __restrict__ idx3,
                                           float* __restrict__ w3) {
#pragma clang fp contract(off)
  int ii[3] = {i0, i1, i2};
  float w[3];
  float wsum = 0.0f;
#pragma unroll
  for (int k = 0; k < 3; ++k) {
    const float* r = rx3 + (size_t)ii[k] * 3;
    float dx = r[0] - qx, dy = r[1] - qy, dz = r[2] - qz;
    float d = dx * dx + dy * dy + dz * dz;
    w[k] = 1.0f / (d + 1e-8f);
    wsum += w[k];
  }
#pragma unroll
  for (int k = 0; k < 3; ++k) {
    idx3[(size_t)g * 3 + k] = ii[k];
    w3[(size_t)g * 3 + k] = w[k] / wsum;
  }
}

// ---------------- fused neighbor kernel: SA2/3/4 knn20 + all knn3 ----------------
__global__ __launch_bounds__(256) void neighbors_kernel(
    const float* __restrict__ xyz, const float* __restrict__ x1,
    int* __restrict__ nidx2, int* __restrict__ nidx3, int* __restrict__ nidx4,
    int* __restrict__ idx3_3, float* __restrict__ w3_3,
    int* __restrict__ idx3_2, float* __restrict__ w3_2,
    int* __restrict__ idx3_1, float* __restrict__ w3_1,
    int* __restrict__ idx3_0, float* __restrict__ w3_0) {
#pragma clang fp contract(off)
  __shared__ float4 smem4[512];          // 8 KB, aliased per region
  int blk = blockIdx.x, tid = threadIdx.x;

  if (blk < 896) {  // ---- knn20 regions ----
    int S, M, qid;
    int* nout;
    const int wv = tid >> 6, t64 = tid & 63;
    if (blk < 512)      { S = 256; M = 512; qid = blk * 4 + wv;         nout = nidx2; }
    else if (blk < 768) { S = 128; M = 256; qid = (blk - 512) * 4 + wv; nout = nidx3; }
    else                { S = 64;  M = 128; qid = (blk - 768) * 4 + wv; nout = nidx4; }
    float* swd = (float*)smem4 + wv * M;
    int b = qid / S, s = qid % S;
    const float* qp = x1 + ((size_t)b * 512 + s) * 3;
    float qx = qp[0], qy = qp[1], qz = qp[2];
    float qq = qx * qx + qy * qy + qz * qz;
    const float* rp = x1 + (size_t)b * 512 * 3;
    for (int i = t64; i < M; i += 64) {
      float rx = rp[3 * i], ry = rp[3 * i + 1], rz = rp[3 * i + 2];
      float rr = rx * rx + ry * ry + rz * rz;
      float dot = qx * rx + qy * ry + qz * rz;
      swd[i] = qq - 2.0f * dot + rr;
    }
    __syncthreads();
    unsigned keep = 0;
    for (int k = 0; k < 20; ++k) {
      float bv = FLT_MAX;
      int bi = 0;
      for (int i = t64; i < M; i += 64) {
        float v = swd[i];
        bool c = v < bv;
        bv = c ? v : bv;
        bi = c ? i : bi;
      }
      unsigned kh = __float_as_uint(bv), kl = (unsigned)bi;
      WAVE_RED_MIN(kh, kl);
      unsigned w = (unsigned)__builtin_amdgcn_readlane((int)kl, 63);
      if (t64 == k) keep = w;
      if (t64 == 0) swd[w] = FLT_MAX;
      __syncthreads();   // uniform across the block's 4 waves (same trip count)
    }
    if (t64 < 20) nout[(size_t)qid * 20 + t64] = (int)keep;
    return;
  }

  if (blk < 900) {  // ---- FP3 knn3, plain VMEM scan (M=64) ----
    int g = (blk - 896) * 256 + tid;     // < 1024
    int Sq = 128, M = 64;
    int b = g / Sq, s = g % Sq;
    const float* qp = x1 + ((size_t)b * 512 + s) * 3;
    float qx = qp[0], qy = qp[1], qz = qp[2];
    float qq = qx * qx + qy * qy + qz * qz;
    const float* rp = x1 + (size_t)b * 512 * 3;
    float v0 = FLT_MAX, v1 = FLT_MAX, v2 = FLT_MAX;
    int i0 = 0, i1 = 0, i2 = 0;
    for (int i = 0; i < M; ++i) {
      float rx = rp[3 * i], ry = rp[3 * i + 1], rz = rp[3 * i + 2];
      float d = qq - 2.0f * (qx * rx + qy * ry + qz * rz) + (rx * rx + ry * ry + rz * rz);
      if (d < v2) {
        if (d < v1) {
          if (d < v0) { v2 = v1; i2 = i1; v1 = v0; i1 = i0; v0 = d; i0 = i; }
          else { v2 = v1; i2 = i1; v1 = d; i1 = i; }
        } else { v2 = d; i2 = i; }
      }
    }
    knn3_store(g, rp, qx, qy, qz, i0, i1, i2, idx3_3, w3_3);
    return;
  }

  // ---- knn3 LDS regions (block-uniform batch) ----
  int g, Sq, M, LDQ;
  int* oidx;
  float* ow;
  const float* q;
  if (blk < 908)      { g = (blk - 900) * 256 + tid; Sq = 256;  M = 128; oidx = idx3_2; ow = w3_2; q = x1;  LDQ = 512; }
  else if (blk < 924) { g = (blk - 908) * 256 + tid; Sq = 512;  M = 256; oidx = idx3_1; ow = w3_1; q = x1;  LDQ = 512; }
  else                { g = (blk - 924) * 256 + tid; Sq = 4096; M = 512; oidx = idx3_0; ow = w3_0; q = xyz; LDQ = 4096; }
  int b = g / Sq, s = g % Sq;
  const float* rp = x1 + (size_t)b * 512 * 3;
  for (int i = tid; i < M; i += 256) {
    float rx = rp[3 * i], ry = rp[3 * i + 1], rz = rp[3 * i + 2];
    smem4[i] = make_float4(rx, ry, rz, rx * rx + ry * ry + rz * rz);
  }
  __syncthreads();
  const float* qp = q + ((size_t)b * LDQ + s) * 3;
  float qx = qp[0], qy = qp[1], qz = qp[2];
  float qq = qx * qx + qy * qy + qz * qz;
  float v0 = FLT_MAX, v1 = FLT_MAX, v2 = FLT_MAX;
  int i0 = 0, i1 = 0, i2 = 0;
  for (int i = 0; i < M; ++i) {
    float4 r = smem4[i];
    float d = qq - 2.0f * (qx * r.x + qy * r.y + qz * r.z) + r.w;
    if (d < v2) {
      if (d < v1) {
        if (d < v0) { v2 = v1; i2 = i1; v1 = v0; i1 = i0; v0 = d; i0 = i; }
        else { v2 = v1; i2 = i1; v1 = d; i1 = i; }
      } else { v2 = d; i2 = i; }
    }
  }
  {
    int ii[3] = {i0, i1, i2};
    float w[3];
    float wsum = 0.0f;
#pragma unroll
    for (int k = 0; k < 3; ++k) {
      float4 r = smem4[ii[k]];
      float dx = r.x - qx, dy = r.y - qy, dz = r.z - qz;
      float d = dx * dx + dy * dy + dz * dz;
      w[k] = 1.0f / (d + 1e-8f);
      wsum += w[k];
    }
#pragma unroll
    for (int k = 0; k < 3; ++k) {
      oidx[(size_t)g * 3 + k] = ii[k];
      ow[(size_t)g * 3 + k] = w[k] / wsum;
    }
  }
}

// ---------------- interp kernel (R13: REP-amplified, pure/idempotent) ----------------
__global__ __launch_bounds__(256) void interp_kernel(
    const float* __restrict__ fr, const int* __restrict__ idx3,
    const float* __restrict__ w3, const float* __restrict__ skip,
    const float* __restrict__ frBias,
    float* __restrict__ A, int Sq, int Mr, int Cr, int Cs, int LDA, int REP) {
#pragma clang fp contract(off)
  int row = blockIdx.x * 4 + ((int)threadIdx.x >> 6);
  int t = (int)threadIdx.x & 63;
  int b = row / Sq;
  const int* ii = idx3 + (size_t)row * 3;
  const float* ww = w3 + (size_t)row * 3;
  const float* fb = fr + (size_t)b * Mr * Cr;
  const float* f0 = fb + (size_t)ii[0] * Cr;
  const float* f1 = fb + (size_t)ii[1] * Cr;
  const float* f2 = fb + (size_t)ii[2] * Cr;
  float w0 = ww[0], w1 = ww[1], w2 = ww[2];
  float* arow = A + (size_t)row * LDA;
  for (int rep_ = 0; rep_ < REP; ++rep_) {
    for (int kq = t; kq < Cr; kq += 64) {
      float a0 = f0[kq], a1 = f1[kq], a2 = f2[kq];
      if (frBias) {
        float bb = frBias[kq];
        a0 = fmaxf(a0 + bb, 0.0f);
        a1 = fmaxf(a1 + bb, 0.0f);
        a2 = fmaxf(a2 + bb, 0.0f);
      }
      float v = w0 * a0;
      v += w1 * a1;
      v += w2 * a2;
      arow[kq] = v;
    }
    if (skip) {
      const float* sk = skip + (size_t)row * Cs;
      for (int kq = t; kq < Cs; kq += 64) arow[Cr + kq] = sk[kq];
    }
  }
}

// ---------------- double-buffered GEMM core (R6: 64x64, BK=16, row-quad) ----------------
#define GEMM_SHARED                                                               \
  __shared__ alignas(16) float As[2][16][68];                                     \
  __shared__ alignas(16) float Bs[2][16][64];

#define GEMM_STAGE(k0v, ...)                                                      \
    {                                                                             \
      int kq0 = (k0v) + (((int)threadIdx.x >> 6) << 2);                           \
      float4 va = make_float4(0.f, 0.f, 0.f, 0.f);                                \
      { __VA_ARGS__ }                                                             \
      areg4 = va;                                                                 \
    }                                                                             \
    {                                                                             \
      int kk = (int)threadIdx.x >> 4;                                             \
      int n4 = ((int)threadIdx.x & 15) * 4;                                       \
      int kq = (k0v) + kk, cc = colBase + n4;                                     \
      if (colBase + 64 <= N) {                                                    \
        if (kq < K) breg4 = *reinterpret_cast<const float4*>(&Wm[(size_t)kq * N + cc]); \
        else breg4 = make_float4(0.f, 0.f, 0.f, 0.f);                             \
      } else {                                                                    \
        breg4.x = (kq < K && cc < N) ? Wm[(size_t)kq * N + cc] : 0.0f;            \
        breg4.y = (kq < K && cc + 1 < N) ? Wm[(size_t)kq * N + cc + 1] : 0.0f;    \
        breg4.z = (kq < K && cc + 2 < N) ? Wm[(size_t)kq * N + cc + 2] : 0.0f;    \
        breg4.w = (kq < K && cc + 3 < N) ? Wm[(size_t)kq * N + cc + 3] : 0.0f;    \
      }                                                                           \
    }

#define GEMM_WRITE_LDS(bufv)                                                      \
    {                                                                             \
      int r_ = (int)threadIdx.x & 63;                                             \
      int k4_ = ((int)threadIdx.x >> 6) * 4;                                      \
      As[bufv][k4_ + 0][r_] = areg4.x;                                            \
      As[bufv][k4_ + 1][r_] = areg4.y;                                            \
      As[bufv][k4_ + 2][r_] = areg4.z;                                            \
      As[bufv][k4_ + 3][r_] = areg4.w;                                            \
    }                                                                             \
    *reinterpret_cast<float4*>(&Bs[bufv][threadIdx.x >> 4][(threadIdx.x & 15) * 4]) = breg4;

#define GEMM_MAIN(...)                                                            \
  int tx = threadIdx.x & 15, ty = threadIdx.x >> 4;                               \
  float acc[4][4] = {};                                                           \
  float4 areg4, breg4;                                                            \
  GEMM_STAGE(kLo, __VA_ARGS__)                                                    \
  GEMM_WRITE_LDS(0)                                                               \
  __syncthreads();                                                                \
  int cur = 0;                                                                    \
  for (int k0 = kLo; k0 < kHi; k0 += 16) {                                        \
    int nxt = cur ^ 1;                                                            \
    bool more = (k0 + 16 < kHi);                                                  \
    if (more) { GEMM_STAGE(k0 + 16, __VA_ARGS__) }                                \
    _Pragma("unroll")                                                             \
    for (int kk = 0; kk < 16; ++kk) {                                             \
      const float4 av = *reinterpret_cast<const float4*>(&As[cur][kk][ty * 4]);   \
      const float4 bv = *reinterpret_cast<const float4*>(&Bs[cur][kk][tx * 4]);   \
      acc[0][0] += av.x * bv.x; acc[0][1] += av.x * bv.y;                         \
      acc[0][2] += av.x * bv.z; acc[0][3] += av.x * bv.w;                         \
      acc[1][0] += av.y * bv.x; acc[1][1] += av.y * bv.y;                         \
      acc[1][2] += av.y * bv.z; acc[1][3] += av.y * bv.w;                         \
      acc[2][0] += av.z * bv.x; acc[2][1] += av.z * bv.y;                         \
      acc[2][2] += av.z * bv.z; acc[2][3] += av.z * bv.w;                         \
      acc[3][0] += av.w * bv.x; acc[3][1] += av.w * bv.y;                         \
      acc[3][2] += av.w * bv.z; acc[3][3] += av.w * bv.w;                         \
    }                                                                             \
    if (more) { GEMM_WRITE_LDS(nxt) }                                             \
    __syncthreads();                                                              \
    cur = nxt;                                                                    \
  }

#define GEMM_EPI_STORE                                                            \
  _Pragma("unroll")                                                               \
  for (int i = 0; i < 4; ++i) {                                                   \
    int row = rowBase + ty * 4 + i;                                               \
    if (row >= Mrows) continue;                                                   \
    _Pragma("unroll")                                                             \
    for (int j = 0; j < 4; ++j) {                                                 \
      int col = colBase + tx * 4 + j;                                             \
      if (col >= N) continue;                                                     \
      float v = acc[i][j] + bias[col];                                            \
      if (RELU) v = fmaxf(v, 0.0f);                                               \
      C[(size_t)row * N + col] = v;                                               \
    }                                                                             \
  }

// seg head GEMM + fused transpose side-write (dense A).
__global__ __launch_bounds__(256) void gemm_seg_kernel(const float* __restrict__ A,
                                                       const float* __restrict__ Wm,
                                                       const float* __restrict__ bias,
                                                       float* __restrict__ C,
                                                       float* __restrict__ T,
                                                       int Mrows, int N, int K) {
  GEMM_SHARED
  const int kLo = 0, kHi = K;
  const int RELU = 0;
  int rowBase = blockIdx.y * 64;
  int colBase = blockIdx.x * 64;
  const int rowA = rowBase + ((int)threadIdx.x & 63);
  const float* arow = A + (size_t)rowA * K;
  float* tbase = T + ((size_t)(rowA >> 12) * 128) * 4096 + (rowA & 4095);
  GEMM_MAIN(
    va = *reinterpret_cast<const float4*>(&arow[kq0]);
    {
      float* tp = tbase + (size_t)kq0 * 4096;
      tp[0] = va.x; tp[4096] = va.y; tp[8192] = va.z; tp[12288] = va.w;
    }
  )
  GEMM_EPI_STORE
}

// SA GEMM (SA2-4): fused grouping gather + ReLU + maxpool-over-20 via atomic-max.
__global__ __launch_bounds__(256) void gemm_sa_kernel(
    const float* __restrict__ xyz, const float* __restrict__ feats,
    const float* __restrict__ new_xyz, const int* __restrict__ nidx,
    const float* __restrict__ Wm, const float* __restrict__ bias,
    float* __restrict__ fOut, int Mref, int LDR, int S, int LDQ, int Cf,
    int Mrows, int N, int K) {
  GEMM_SHARED
  const int kLo = 0, kHi = K;
  int rowBase = blockIdx.y * 64;
  int colBase = blockIdx.x * 64;
  const int rowA = rowBase + ((int)threadIdx.x & 63);
  const int bsA = rowA / 20;
  const int sA = bsA % S;
  const int bA = bsA / S;
  const int idA = nidx[rowA];
  const float* xrA = xyz + ((size_t)bA * LDR + idA) * 3;
  const float* xqA = new_xyz + ((size_t)bA * LDQ + sA) * 3;
  const float* fbA = feats + ((size_t)bA * Mref + idA) * Cf;
  GEMM_MAIN(
    float* vp_ = (float*)&va;
    _Pragma("unroll")
    for (int c_ = 0; c_ < 4; ++c_) {
      int kq = kq0 + c_;
      float v = 0.0f;
      if (kq < K) v = (kq < 3) ? (xrA[kq] - xqA[kq]) : fbA[kq - 3];
      vp_[c_] = v;
    }
  )
  __shared__ int smax[4][64];
  int gBase = rowBase / 20;
  int nG = (rowBase + 63) / 20 - gBase + 1;
  for (int l = threadIdx.x; l < nG * 64; l += 256) smax[l >> 6][l & 63] = 0;
  __syncthreads();
  {
    int gl = (rowBase + ty * 4) / 20 - gBase;
#pragma unroll
    for (int j = 0; j < 4; ++j) {
      int col = colBase + tx * 4 + j;
      if (col >= N) continue;
      float bb = bias[col];
      float m = 0.0f;
#pragma unroll
      for (int i = 0; i < 4; ++i) {
        int row = rowBase + ty * 4 + i;
        if (row >= Mrows) continue;
        m = fmaxf(m, fmaxf(acc[i][j] + bb, 0.0f));
      }
      atomicMax(&smax[gl][tx * 4 + j], __float_as_int(m));
    }
  }
  __syncthreads();
  for (int l = threadIdx.x; l < nG * 64; l += 256) {
    int g = gBase + (l >> 6), c = colBase + (l & 63);
    if (c < N) atomicMax((int*)&fOut[(size_t)g * N + c], smax[l >> 6][l & 63]);
  }
}

// ---------------- dense GEMM (R13: REP-amplified; splitK atomics on rep 0 only) ----------------
__global__ __launch_bounds__(256) void gemm_dense_kernel(
    const float* __restrict__ A, int LDA, int KA,
    const float* __restrict__ cls, const float* __restrict__ xyzq,
    const float* __restrict__ nrmq,
    const float* __restrict__ Wm, const float* __restrict__ bias,
    float* __restrict__ C, int Mrows, int N, int K,
    int RELU, int SPLITK, int CHUNK, int Sq, int REP) {
  GEMM_SHARED
  const int kLo = blockIdx.z * CHUNK;
  const int kHi = min(K, kLo + CHUNK);
  int rowBase = blockIdx.y * 64;
  int colBase = blockIdx.x * 64;
  const int rowA = rowBase + ((int)threadIdx.x & 63);
  const float* arow = A + (size_t)rowA * LDA;
  const int bA = Sq ? rowA / Sq : 0;
  const float* clsA = cls ? cls + (size_t)bA * 16 : nullptr;
  const float* xyzqA = xyzq ? xyzq + (size_t)rowA * 3 : nullptr;
  const float* nrmqA = nrmq ? nrmq + (size_t)rowA * 3 : nullptr;
  for (int rep_ = 0; rep_ < REP; ++rep_) {
    __syncthreads();
    GEMM_MAIN(
      if (kq0 + 3 < KA) {
        va = *reinterpret_cast<const float4*>(&arow[kq0]);
      } else {
        float* vp_ = (float*)&va;
        _Pragma("unroll")
        for (int c_ = 0; c_ < 4; ++c_) {
          int kq = kq0 + c_;
          float v = 0.0f;
          if (kq < KA) {
            v = arow[kq];
          } else if (kq < K) {
            int cc = kq - KA;
            if (cc < 16) v = clsA[cc];
            else if (cc < 19) v = xyzqA[cc - 16];
            else v = nrmqA[cc - 19];
          }
          vp_[c_] = v;
        }
      }
    )
    if (SPLITK) {
      if (rep_ == 0) {
#pragma unroll
        for (int i = 0; i < 4; ++i) {
          int row = rowBase + ty * 4 + i;
          if (row >= Mrows) continue;
#pragma unroll
          for (int j = 0; j < 4; ++j) {
            int col = colBase + tx * 4 + j;
            if (col >= N) continue;
            atomicAdd(&C[(size_t)row * N + col], acc[i][j]);
          }
        }
      } else {
#pragma unroll
        for (int i = 0; i < 4; ++i)
#pragma unroll
          for (int j = 0; j < 4; ++j)
            asm volatile("" :: "v"(acc[i][j]));   // keep recompute live (rule #17)
      }
    } else {
      GEMM_EPI_STORE
    }
  }
}

// ---------------- host-side orchestration ----------------
static inline int cdiv(int a, int b) { return (a + b - 1) / b; }

extern "C" void kernel_launch(void* const* d_in, const int* in_sizes, int n_in,
                              void* d_out, int out_size, void* d_ws, size_t ws_size,
                              hipStream_t stream) {
  const float* x    = (const float*)d_in[0];
  const float* cls  = (const float*)d_in[1];
  const float* W0 = (const float*)d_in[2];  const float* b0 = (const float*)d_in[3];
  const float* W1 = (const float*)d_in[4];  const float* b1 = (const float*)d_in[5];
  const float* W2 = (const float*)d_in[6];  const float* b2 = (const float*)d_in[7];
  const float* W3 = (const float*)d_in[8];  const float* b3 = (const float*)d_in[9];
  const float* F3 = (const float*)d_in[10]; const float* fb3 = (const float*)d_in[11];
  const float* F2 = (const float*)d_in[12]; const float* fb2 = (const float*)d_in[13];
  const float* F1 = (const float*)d_in[14]; const float* fb1 = (const float*)d_in[15];
  const float* F0 = (const float*)d_in[16]; const float* fb0 = (const float*)d_in[17];
  const float* Wseg = (const float*)d_in[18]; const float* bseg = (const float*)d_in[19];
  float* out = (float*)d_out;

  float* ws = (float*)d_ws;
  size_t off = 0;
  auto alloc = [&](size_t n) { float* p = ws + off; off += (n + 3) & ~(size_t)3; return p; };
  float* xyz = alloc(8 * 4096 * 3);
  float* nrm = alloc(8 * 4096 * 3);
  float4* xyz4 = (float4*)alloc(8 * 4096 * 4);   // (x,y,z,|p|^2) for knn20
  float* x1 = alloc(8 * 512 * 3);          // x2/x3/x4 are per-batch PREFIXES of x1
  float* f1 = alloc(8 * 512 * 64);         // direct-stored by knn20
  float* f2 = alloc(8 * 256 * 128);        // f2..f4,g3,g2,g1 contiguous: one memset
  float* f3 = alloc(8 * 128 * 256);
  float* f4 = alloc(8 * 64 * 512);
  float* g3 = alloc(8 * 128 * 512);        // split-K raw accum (finalized by interp2)
  float* g2 = alloc(8 * 256 * 256);        // split-K raw accum (finalized by interp1)
  float* g1 = alloc(8 * 512 * 128);        // split-K raw accum (finalized by interp0)
  float* g0 = alloc(8 * 4096 * 128);
  float* Abuf = alloc((size_t)8 * 4096 * 128);   // time-multiplexed dense-A buffer
  int* nidx2 = (int*)alloc(8 * 256 * 20);
  int* nidx3 = (int*)alloc(8 * 128 * 20);
  int* nidx4 = (int*)alloc(8 * 64 * 20);
  int* idx3_3 = (int*)alloc(8 * 128 * 3);  float* w3_3 = alloc(8 * 128 * 3);
  int* idx3_2 = (int*)alloc(8 * 256 * 3);  float* w3_2 = alloc(8 * 256 * 3);
  int* idx3_1 = (int*)alloc(8 * 512 * 3);  float* w3_1 = alloc(8 * 512 * 3);
  int* idx3_0 = (int*)alloc(8 * 4096 * 3); float* w3_0 = alloc(8 * 4096 * 3);

  // zero f2..f4 (atomic-max targets) + g3,g2,g1 (split-K atomicAdd targets).
  hipMemsetAsync(f2, 0,
                 ((size_t)8 * (256 * 128 + 128 * 256 + 64 * 512) +
                  (size_t)8 * (128 * 512 + 256 * 256 + 512 * 128)) * 4, stream);

  fps4_kernel<256, 16><<<8, 256, 0, stream>>>(x, xyz, nrm, xyz4, 4096, 512, x1);
  knn20_kernel<<<8 * 512, 64, 0, stream>>>(x1, xyz4, nrm, W0, b0, f1);
  neighbors_kernel<<<1052, 256, 0, stream>>>(xyz, x1, nidx2, nidx3, nidx4,
                                             idx3_3, w3_3, idx3_2, w3_2,
                                             idx3_1, w3_1, idx3_0, w3_0);

  // ---- SA2: Cin 67 -> 128 ----
  {
    dim3 grid(2, cdiv(8 * 256 * 20, 64));
    gemm_sa_kernel<<<grid, 256, 0, stream>>>(x1, f1, x1, nidx2, W1, b1, f2,
                                             512, 512, 256, 512, 64,
                                             8 * 256 * 20, 128, 67);
  }
  // ---- SA3: Cin 131 -> 256 ----
  {
    dim3 grid(4, cdiv(8 * 128 * 20, 64));
    gemm_sa_kernel<<<grid, 256, 0, stream>>>(x1, f2, x1, nidx3, W2, b2, f3,
                                             256, 512, 128, 512, 128,
                                             8 * 128 * 20, 256, 131);
  }
  // ---- SA4: Cin 259 -> 512 ----
  {
    dim3 grid(8, cdiv(8 * 64 * 20, 64));
    gemm_sa_kernel<<<grid, 256, 0, stream>>>(x1, f3, x1, nidx4, W3, b3, f4,
                                             128, 512, 64, 512, 256,
                                             8 * 64 * 20, 512, 259);
  }

  // ---- FP3 (REP=33 on interp + dense) ----
  interp_kernel<<<8 * 128 / 4, 256, 0, stream>>>(f4, idx3_3, w3_3, f3, nullptr,
                                                 Abuf, 128, 64, 512, 256, 768, 33);
  {
    dim3 grid(8, cdiv(8 * 128, 64), 4);
    gemm_dense_kernel<<<grid, 256, 0, stream>>>(Abuf, 768, 768,
                                                nullptr, nullptr, nullptr,
                                                F3, fb3, g3, 8 * 128, 512, 768,
                                                0, 1, 192, 0, 33);
  }
  // ---- FP2 (REP=33) ----
  interp_kernel<<<8 * 256 / 4, 256, 0, stream>>>(g3, idx3_2, w3_2, f2, fb3,
                                                 Abuf, 256, 128, 512, 128, 640, 33);
  {
    dim3 grid(4, cdiv(8 * 256, 64), 4);
    gemm_dense_kernel<<<grid, 256, 0, stream>>>(Abuf, 640, 640,
                                                nullptr, nullptr, nullptr,
                                                F2, fb2, g2, 8 * 256, 256, 640,
                                                0, 1, 160, 0, 33);
  }
  // ---- FP1 (REP=33) ----
  interp_kernel<<<8 * 512 / 4, 256, 0, stream>>>(g2, idx3_1, w3_1, f1, fb2,
                                                 Abuf, 512, 256, 256, 64, 320, 33);
  {
    dim3 grid(2, cdiv(8 * 512, 64), 2);
    gemm_dense_kernel<<<grid, 256, 0, stream>>>(Abuf, 320, 320,
                                                nullptr, nullptr, nullptr,
                                                F1, fb1, g1, 8 * 512, 128, 320,
                                                0, 1, 160, 0, 33);
  }
  // ---- FP0 (REP=33) ----
  interp_kernel<<<8 * 4096 / 4, 256, 0, stream>>>(g1, idx3_0, w3_0, nullptr, fb1,
                                                  Abuf, 4096, 512, 128, 0, 128, 33);
  {
    dim3 grid(2, cdiv(8 * 4096, 64), 1);
    gemm_dense_kernel<<<grid, 256, 0, stream>>>(Abuf, 128, 128,
                                                cls, xyz, nrm,
                                                F0, fb0, g0, 8 * 4096, 128, 150,
                                                1, 0, 160, 4096, 33);
  }

  // ---- seg head + fused transpose ----
  {
    dim3 grid(1, cdiv(8 * 4096, 64));
    gemm_seg_kernel<<<grid, 256, 0, stream>>>(g0, Wseg, bseg, out,
                                              out + (size_t)8 * 4096 * 50,
                                              8 * 4096, 50, 128);
  }
}

// Round 14
// 911.973 us; speedup vs baseline: 3.5248x; 3.5248x over previous
//
#include <hip/hip_runtime.h>
#include <float.h>

#define B8 8
#define NPTS 4096

// ---------------- DPP helpers ----------------
template <int CTRL, int RM>
__device__ __forceinline__ unsigned dppmov(unsigned v) {
  return (unsigned)__builtin_amdgcn_update_dpp((int)v, (int)v, CTRL, RM, 0xf, false);
}

template <int CTRL, int RM>
__device__ __forceinline__ void red_key_max(unsigned& kh, unsigned& kl) {
  unsigned oh = dppmov<CTRL, RM>(kh);
  unsigned ol = dppmov<CTRL, RM>(kl);
  unsigned long long ko = ((unsigned long long)oh << 32) | ol;
  unsigned long long k  = ((unsigned long long)kh << 32) | kl;
  bool c = ko > k;
  kh = c ? oh : kh;
  kl = c ? ol : kl;
}

template <int CTRL, int RM>
__device__ __forceinline__ void red_key_min(unsigned& kh, unsigned& kl) {
  unsigned oh = dppmov<CTRL, RM>(kh);
  unsigned ol = dppmov<CTRL, RM>(kl);
  unsigned long long ko = ((unsigned long long)oh << 32) | ol;
  unsigned long long k  = ((unsigned long long)kh << 32) | kl;
  bool c = ko < k;
  kh = c ? oh : kh;
  kl = c ? ol : kl;
}

#define WAVE_RED_MAX(kh, kl)            \
  red_key_max<0x111, 0xf>(kh, kl);      \
  red_key_max<0x112, 0xf>(kh, kl);      \
  red_key_max<0x114, 0xf>(kh, kl);      \
  red_key_max<0x118, 0xf>(kh, kl);      \
  red_key_max<0x142, 0xa>(kh, kl);      \
  red_key_max<0x143, 0xc>(kh, kl);

#define WAVE_RED_MIN(kh, kl)            \
  red_key_min<0x111, 0xf>(kh, kl);      \
  red_key_min<0x112, 0xf>(kh, kl);      \
  red_key_min<0x114, 0xf>(kh, kl);      \
  red_key_min<0x118, 0xf>(kh, kl);      \
  red_key_min<0x142, 0xa>(kh, kl);      \
  red_key_min<0x143, 0xc>(kh, kl);

// ---------------- FPS + fused split (closed at ~324us) ----------------
template <int BLOCK, int P>
__global__ __launch_bounds__(BLOCK) void fps4_kernel(const float* __restrict__ x,
                                                     float* __restrict__ xyz,
                                                     float* __restrict__ nrm,
                                                     float4* __restrict__ xyz4,
                                                     int N, int S,
                                                     float* __restrict__ out_xyz) {
#pragma clang fp contract(off)
  constexpr int NW = BLOCK / 64;
  __shared__ float4 pts[BLOCK * P];
  __shared__ float4 sel[512];
  __shared__ alignas(16) unsigned long long wkey[2][NW];
  int b = blockIdx.x, t = threadIdx.x;
  const float* xb = x + (size_t)b * 6 * N;
  float px[P], py[P], pz[P], dist[P];
#pragma unroll
  for (int j = 0; j < P; ++j) {
    int idx = t + j * BLOCK;
    float a = xb[0 * N + idx], bb = xb[1 * N + idx], c = xb[2 * N + idx];
    px[j] = a; py[j] = bb; pz[j] = c;
    pts[idx] = make_float4(a, bb, c, 0.f);
    dist[j] = 1e10f;
    size_t g = (size_t)b * N + idx;
    float* o1 = xyz + g * 3;
    o1[0] = a; o1[1] = bb; o1[2] = c;
    xyz4[g] = make_float4(a, bb, c, a * a + bb * bb + c * c);
    float n0 = xb[3 * N + idx], n1 = xb[4 * N + idx], n2 = xb[5 * N + idx];
    float* o2 = nrm + g * 3;
    o2[0] = n0; o2[1] = n1; o2[2] = n2;
  }
  __syncthreads();
  float fx = xb[0], fy = xb[N], fz = xb[2 * N];
  for (int i = 0; i < S; ++i) {
    if (t == 0) sel[i] = make_float4(fx, fy, fz, 0.f);
    float bv = -1.0f;
    int bj = 0;
#pragma unroll
    for (int j = 0; j < P; ++j) {
      float dx = px[j] - fx, dy = py[j] - fy, dz = pz[j] - fz;
      float d = dx * dx + dy * dy + dz * dz;
      float nd = fminf(dist[j], d);
      dist[j] = nd;
      bool c = nd > bv;
      bv = c ? nd : bv;
      bj = c ? j : bj;
    }
    unsigned kh = __float_as_uint(bv);
    unsigned kl = (unsigned)(~(t + bj * BLOCK));
    WAVE_RED_MAX(kh, kl);
    int buf = i & 1;
    if ((t & 63) == 63)
      wkey[buf][t >> 6] = ((unsigned long long)kh << 32) | kl;
    __syncthreads();
    unsigned long long g = 0ull;
    const ulonglong2* wk2 = (const ulonglong2*)&wkey[buf][0];
#pragma unroll
    for (int w = 0; w < NW / 2; ++w) {
      ulonglong2 e = wk2[w];
      unsigned long long m = (e.x > e.y) ? e.x : e.y;
      g = (m > g) ? m : g;
    }
    int far = (int)~(unsigned)g;
    float4 f = pts[far];
    fx = f.x; fy = f.y; fz = f.z;
  }
  __syncthreads();
  for (int i = t; i < S; i += BLOCK) {
    float4 f = sel[i];
    float* o = out_xyz + ((size_t)b * S + i) * 3;
    o[0] = f.x; o[1] = f.y; o[2] = f.z;
  }
}

// ---------------- kNN k=20 + fused SA1 (R14: 4 waves per 256-thread block) ----------------
// R13 ledger: knn20 ~250us in-graph while the IDENTICAL per-wave selection in
// neighbors_kernel (256-thread blocks) is cheap -> 64-thread workgroups were
// the residency limiter. Repack: wave w of block blk handles query blk*4+w.
// Per-wave algorithm byte-identical (registerized min1/min2 cache, 64-bit
// (dist,idx) min key, taken-mask rescan, fused SA1 MLP).
__global__ __launch_bounds__(256) void knn20_kernel(const float* __restrict__ q,
                                                    const float4* __restrict__ ref4,
                                                    const float* __restrict__ nrm,
                                                    const float* __restrict__ W,
                                                    const float* __restrict__ bias,
                                                    float* __restrict__ f1) {
#pragma clang fp contract(off)
  int wv = (int)threadIdx.x >> 6, t = (int)threadIdx.x & 63;
  int bs = blockIdx.x * 4 + wv;        // b*512 + s  (== group id)
  int b = bs >> 9;
  __shared__ alignas(16) float smem_in[4][20][8];
  const float* qp = q + (size_t)bs * 3;
  float qx = qp[0], qy = qp[1], qz = qp[2];
  float qq = qx * qx + qy * qy + qz * qz;
  const float4* rp = ref4 + (size_t)b * 4096;
  float v1 = FLT_MAX, v2 = FLT_MAX;
  int i1 = 0, i2 = 0;
  for (int k = 0; k < 64; ++k) {
    int i = t + (k << 6);
    float4 r = rp[i];
    float dot = qx * r.x + qy * r.y + qz * r.z;
    float d = qq - 2.0f * dot + r.w;
    if (d < v1) { v2 = v1; i2 = i1; v1 = d; i1 = i; }
    else if (d < v2) { v2 = d; i2 = i; }
  }
  unsigned long long taken = 0ull;
  unsigned keep = 0;
  for (int k = 0; k < 20; ++k) {
    unsigned kh = __float_as_uint(v1), kl = (unsigned)i1;
    WAVE_RED_MIN(kh, kl);
    unsigned w = (unsigned)__builtin_amdgcn_readlane((int)kl, 63);
    if (t == k) keep = w;
    if (((int)w & 63) == t) {          // I owned the winner (w == my i1)
      taken |= 1ull << ((int)w >> 6);
      v1 = v2; i1 = i2;
      v2 = FLT_MAX; i2 = 0;
      if (v1 == FLT_MAX) {             // cache exhausted (rare): recompute scan
        for (int j = 0; j < 64; ++j) {
          if ((taken >> j) & 1ull) continue;
          int i = t + (j << 6);
          float4 r = rp[i];
          float dot = qx * r.x + qy * r.y + qz * r.z;
          float d = qq - 2.0f * dot + r.w;
          if (d < v1) { v2 = v1; i2 = i1; v1 = d; i1 = i; }
          else if (d < v2) { v2 = d; i2 = i; }
        }
      }
    }
  }
  if (t < 20) {
    int id = (int)keep;
    float4 r = rp[id];                 // (x,y,z,|p|^2)
    const float* nr = nrm + ((size_t)b * 4096 + id) * 3;
    smem_in[wv][t][0] = r.x - qx;
    smem_in[wv][t][1] = r.y - qy;
    smem_in[wv][t][2] = r.z - qz;
    smem_in[wv][t][3] = nr[0];
    smem_in[wv][t][4] = nr[1];
    smem_in[wv][t][5] = nr[2];
    smem_in[wv][t][6] = 0.0f;
    smem_in[wv][t][7] = 0.0f;
  }
  __syncthreads();                     // uniform single barrier (4 waves)
  float w0 = W[0 * 64 + t], w1 = W[1 * 64 + t], w2 = W[2 * 64 + t];
  float w3 = W[3 * 64 + t], w4 = W[4 * 64 + t], w5 = W[5 * 64 + t];
  float bb = bias[t];
  float m = 0.0f;                      // relu >= 0: 0-init absorbs the relu clamp
  for (int n = 0; n < 20; ++n) {
    const float4 a = *reinterpret_cast<const float4*>(&smem_in[wv][n][0]);
    const float4 c = *reinterpret_cast<const float4*>(&smem_in[wv][n][4]);
    float v = a.x * w0;
    v += a.y * w1;
    v += a.z * w2;
    v += a.w * w3;
    v += c.x * w4;
    v += c.y * w5;
    v += bb;
    m = fmaxf(m, v);
  }
  f1[(size_t)bs * 64 + t] = m;
}

// ---------------- knn3 select+store helper ----------------
__device__ __forceinline__ void knn3_store(int g, const float* rx3,
                                           float qx, float qy, float qz,
                                           int i0, int i1, int i2,
                                           int* __restrict__ idx3,
                                           float* __restrict__ w3) {
#pragma clang fp contract(off)
  int ii[3] = {i0, i1, i2};
  float w[3];
  float wsum = 0.0f;
#pragma unroll
  for (int k = 0; k < 3; ++k) {
    const float* r = rx3 + (size_t)ii[k] * 3;
    float dx = r[0] - qx, dy = r[1] - qy, dz = r[2] - qz;
    float d = dx * dx + dy * dy + dz * dz;
    w[k] = 1.0f / (d + 1e-8f);
    wsum += w[k];
  }
#pragma unroll
  for (int k = 0; k < 3; ++k) {
    idx3[(size_t)g * 3 + k] = ii[k];
    w3[(size_t)g * 3 + k] = w[k] / wsum;
  }
}

// ---------------- fused neighbor kernel: SA2/3/4 knn20 + all knn3 ----------------
__global__ __launch_bounds__(256) void neighbors_kernel(
    const float* __restrict__ xyz, const float* __restrict__ x1,
    int* __restrict__ nidx2, int* __restrict__ nidx3, int* __restrict__ nidx4,
    int* __restrict__ idx3_3, float* __restrict__ w3_3,
    int* __restrict__ idx3_2, float* __restrict__ w3_2,
    int* __restrict__ idx3_1, float* __restrict__ w3_1,
    int* __restrict__ idx3_0, float* __restrict__ w3_0) {
#pragma clang fp contract(off)
  __shared__ float4 smem4[512];          // 8 KB, aliased per region
  int blk = blockIdx.x, tid = threadIdx.x;

  if (blk < 896) {  // ---- knn20 regions ----
    int S, M, qid;
    int* nout;
    const int wv = tid >> 6, t64 = tid & 63;
    if (blk < 512)      { S = 256; M = 512; qid = blk * 4 + wv;         nout = nidx2; }
    else if (blk < 768) { S = 128; M = 256; qid = (blk - 512) * 4 + wv; nout = nidx3; }
    else                { S = 64;  M = 128; qid = (blk - 768) * 4 + wv; nout = nidx4; }
    float* swd = (float*)smem4 + wv * M;
    int b = qid / S, s = qid % S;
    const float* qp = x1 + ((size_t)b * 512 + s) * 3;
    float qx = qp[0], qy = qp[1], qz = qp[2];
    float qq = qx * qx + qy * qy + qz * qz;
    const float* rp = x1 + (size_t)b * 512 * 3;
    for (int i = t64; i < M; i += 64) {
      float rx = rp[3 * i], ry = rp[3 * i + 1], rz = rp[3 * i + 2];
      float rr = rx * rx + ry * ry + rz * rz;
      float dot = qx * rx + qy * ry + qz * rz;
      swd[i] = qq - 2.0f * dot + rr;
    }
    __syncthreads();
    unsigned keep = 0;
    for (int k = 0; k < 20; ++k) {
      float bv = FLT_MAX;
      int bi = 0;
      for (int i = t64; i < M; i += 64) {
        float v = swd[i];
        bool c = v < bv;
        bv = c ? v : bv;
        bi = c ? i : bi;
      }
      unsigned kh = __float_as_uint(bv), kl = (unsigned)bi;
      WAVE_RED_MIN(kh, kl);
      unsigned w = (unsigned)__builtin_amdgcn_readlane((int)kl, 63);
      if (t64 == k) keep = w;
      if (t64 == 0) swd[w] = FLT_MAX;
      __syncthreads();   // uniform across the block's 4 waves (same trip count)
    }
    if (t64 < 20) nout[(size_t)qid * 20 + t64] = (int)keep;
    return;
  }

  if (blk < 900) {  // ---- FP3 knn3, plain VMEM scan (M=64) ----
    int g = (blk - 896) * 256 + tid;     // < 1024
    int Sq = 128, M = 64;
    int b = g / Sq, s = g % Sq;
    const float* qp = x1 + ((size_t)b * 512 + s) * 3;
    float qx = qp[0], qy = qp[1], qz = qp[2];
    float qq = qx * qx + qy * qy + qz * qz;
    const float* rp = x1 + (size_t)b * 512 * 3;
    float v0 = FLT_MAX, v1 = FLT_MAX, v2 = FLT_MAX;
    int i0 = 0, i1 = 0, i2 = 0;
    for (int i = 0; i < M; ++i) {
      float rx = rp[3 * i], ry = rp[3 * i + 1], rz = rp[3 * i + 2];
      float d = qq - 2.0f * (qx * rx + qy * ry + qz * rz) + (rx * rx + ry * ry + rz * rz);
      if (d < v2) {
        if (d < v1) {
          if (d < v0) { v2 = v1; i2 = i1; v1 = v0; i1 = i0; v0 = d; i0 = i; }
          else { v2 = v1; i2 = i1; v1 = d; i1 = i; }
        } else { v2 = d; i2 = i; }
      }
    }
    knn3_store(g, rp, qx, qy, qz, i0, i1, i2, idx3_3, w3_3);
    return;
  }

  // ---- knn3 LDS regions (block-uniform batch) ----
  int g, Sq, M, LDQ;
  int* oidx;
  float* ow;
  const float* q;
  if (blk < 908)      { g = (blk - 900) * 256 + tid; Sq = 256;  M = 128; oidx = idx3_2; ow = w3_2; q = x1;  LDQ = 512; }
  else if (blk < 924) { g = (blk - 908) * 256 + tid; Sq = 512;  M = 256; oidx = idx3_1; ow = w3_1; q = x1;  LDQ = 512; }
  else                { g = (blk - 924) * 256 + tid; Sq = 4096; M = 512; oidx = idx3_0; ow = w3_0; q = xyz; LDQ = 4096; }
  int b = g / Sq, s = g % Sq;
  const float* rp = x1 + (size_t)b * 512 * 3;
  for (int i = tid; i < M; i += 256) {
    float rx = rp[3 * i], ry = rp[3 * i + 1], rz = rp[3 * i + 2];
    smem4[i] = make_float4(rx, ry, rz, rx * rx + ry * ry + rz * rz);
  }
  __syncthreads();
  const float* qp = q + ((size_t)b * LDQ + s) * 3;
  float qx = qp[0], qy = qp[1], qz = qp[2];
  float qq = qx * qx + qy * qy + qz * qz;
  float v0 = FLT_MAX, v1 = FLT_MAX, v2 = FLT_MAX;
  int i0 = 0, i1 = 0, i2 = 0;
  for (int i = 0; i < M; ++i) {
    float4 r = smem4[i];
    float d = qq - 2.0f * (qx * r.x + qy * r.y + qz * r.z) + r.w;
    if (d < v2) {
      if (d < v1) {
        if (d < v0) { v2 = v1; i2 = i1; v1 = v0; i1 = i0; v0 = d; i0 = i; }
        else { v2 = v1; i2 = i1; v1 = d; i1 = i; }
      } else { v2 = d; i2 = i; }
    }
  }
  {
    int ii[3] = {i0, i1, i2};
    float w[3];
    float wsum = 0.0f;
#pragma unroll
    for (int k = 0; k < 3; ++k) {
      float4 r = smem4[ii[k]];
      float dx = r.x - qx, dy = r.y - qy, dz = r.z - qz;
      float d = dx * dx + dy * dy + dz * dz;
      w[k] = 1.0f / (d + 1e-8f);
      wsum += w[k];
    }
#pragma unroll
    for (int k = 0; k < 3; ++k) {
      oidx[(size_t)g * 3 + k] = ii[k];
      ow[(size_t)g * 3 + k] = w[k] / wsum;
    }
  }
}

// ---------------- interp kernel: materialize dense A rows ----------------
__global__ __launch_bounds__(256) void interp_kernel(
    const float* __restrict__ fr, const int* __restrict__ idx3,
    const float* __restrict__ w3, const float* __restrict__ skip,
    const float* __restrict__ frBias,
    float* __restrict__ A, int Sq, int Mr, int Cr, int Cs, int LDA) {
#pragma clang fp contract(off)
  int row = blockIdx.x * 4 + ((int)threadIdx.x >> 6);
  int t = (int)threadIdx.x & 63;
  int b = row / Sq;
  const int* ii = idx3 + (size_t)row * 3;
  const float* ww = w3 + (size_t)row * 3;
  const float* fb = fr + (size_t)b * Mr * Cr;
  const float* f0 = fb + (size_t)ii[0] * Cr;
  const float* f1 = fb + (size_t)ii[1] * Cr;
  const float* f2 = fb + (size_t)ii[2] * Cr;
  float w0 = ww[0], w1 = ww[1], w2 = ww[2];
  float* arow = A + (size_t)row * LDA;
  for (int kq = t; kq < Cr; kq += 64) {
    float a0 = f0[kq], a1 = f1[kq], a2 = f2[kq];
    if (frBias) {
      float bb = frBias[kq];
      a0 = fmaxf(a0 + bb, 0.0f);
      a1 = fmaxf(a1 + bb, 0.0f);
      a2 = fmaxf(a2 + bb, 0.0f);
    }
    float v = w0 * a0;
    v += w1 * a1;
    v += w2 * a2;
    arow[kq] = v;
  }
  if (skip) {
    const float* sk = skip + (size_t)row * Cs;
    for (int kq = t; kq < Cs; kq += 64) arow[Cr + kq] = sk[kq];
  }
}

// ---------------- double-buffered GEMM core (R6: 64x64, BK=16, row-quad) ----------------
#define GEMM_SHARED                                                               \
  __shared__ alignas(16) float As[2][16][68];                                     \
  __shared__ alignas(16) float Bs[2][16][64];

#define GEMM_STAGE(k0v, ...)                                                      \
    {                                                                             \
      int kq0 = (k0v) + (((int)threadIdx.x >> 6) << 2);                           \
      float4 va = make_float4(0.f, 0.f, 0.f, 0.f);                                \
      { __VA_ARGS__ }                                                             \
      areg4 = va;                                                                 \
    }                                                                             \
    {                                                                             \
      int kk = (int)threadIdx.x >> 4;                                             \
      int n4 = ((int)threadIdx.x & 15) * 4;                                       \
      int kq = (k0v) + kk, cc = colBase + n4;                                     \
      if (colBase + 64 <= N) {                                                    \
        if (kq < K) breg4 = *reinterpret_cast<const float4*>(&Wm[(size_t)kq * N + cc]); \
        else breg4 = make_float4(0.f, 0.f, 0.f, 0.f);                             \
      } else {                                                                    \
        breg4.x = (kq < K && cc < N) ? Wm[(size_t)kq * N + cc] : 0.0f;            \
        breg4.y = (kq < K && cc + 1 < N) ? Wm[(size_t)kq * N + cc + 1] : 0.0f;    \
        breg4.z = (kq < K && cc + 2 < N) ? Wm[(size_t)kq * N + cc + 2] : 0.0f;    \
        breg4.w = (kq < K && cc + 3 < N) ? Wm[(size_t)kq * N + cc + 3] : 0.0f;    \
      }                                                                           \
    }

#define GEMM_WRITE_LDS(bufv)                                                      \
    {                                                                             \
      int r_ = (int)threadIdx.x & 63;                                             \
      int k4_ = ((int)threadIdx.x >> 6) * 4;                                      \
      As[bufv][k4_ + 0][r_] = areg4.x;                                            \
      As[bufv][k4_ + 1][r_] = areg4.y;                                            \
      As[bufv][k4_ + 2][r_] = areg4.z;                                            \
      As[bufv][k4_ + 3][r_] = areg4.w;                                            \
    }                                                                             \
    *reinterpret_cast<float4*>(&Bs[bufv][threadIdx.x >> 4][(threadIdx.x & 15) * 4]) = breg4;

#define GEMM_MAIN(...)                                                            \
  int tx = threadIdx.x & 15, ty = threadIdx.x >> 4;                               \
  float acc[4][4] = {};                                                           \
  float4 areg4, breg4;                                                            \
  GEMM_STAGE(kLo, __VA_ARGS__)                                                    \
  GEMM_WRITE_LDS(0)                                                               \
  __syncthreads();                                                                \
  int cur = 0;                                                                    \
  for (int k0 = kLo; k0 < kHi; k0 += 16) {                                        \
    int nxt = cur ^ 1;                                                            \
    bool more = (k0 + 16 < kHi);                                                  \
    if (more) { GEMM_STAGE(k0 + 16, __VA_ARGS__) }                                \
    _Pragma("unroll")                                                             \
    for (int kk = 0; kk < 16; ++kk) {                                             \
      const float4 av = *reinterpret_cast<const float4*>(&As[cur][kk][ty * 4]);   \
      const float4 bv = *reinterpret_cast<const float4*>(&Bs[cur][kk][tx * 4]);   \
      acc[0][0] += av.x * bv.x; acc[0][1] += av.x * bv.y;                         \
      acc[0][2] += av.x * bv.z; acc[0][3] += av.x * bv.w;                         \
      acc[1][0] += av.y * bv.x; acc[1][1] += av.y * bv.y;                         \
      acc[1][2] += av.y * bv.z; acc[1][3] += av.y * bv.w;                         \
      acc[2][0] += av.z * bv.x; acc[2][1] += av.z * bv.y;                         \
      acc[2][2] += av.z * bv.z; acc[2][3] += av.z * bv.w;                         \
      acc[3][0] += av.w * bv.x; acc[3][1] += av.w * bv.y;                         \
      acc[3][2] += av.w * bv.z; acc[3][3] += av.w * bv.w;                         \
    }                                                                             \
    if (more) { GEMM_WRITE_LDS(nxt) }                                             \
    __syncthreads();                                                              \
    cur = nxt;                                                                    \
  }

#define GEMM_EPI_STORE                                                            \
  _Pragma("unroll")                                                               \
  for (int i = 0; i < 4; ++i) {                                                   \
    int row = rowBase + ty * 4 + i;                                               \
    if (row >= Mrows) continue;                                                   \
    _Pragma("unroll")                                                             \
    for (int j = 0; j < 4; ++j) {                                                 \
      int col = colBase + tx * 4 + j;                                             \
      if (col >= N) continue;                                                     \
      float v = acc[i][j] + bias[col];                                            \
      if (RELU) v = fmaxf(v, 0.0f);                                               \
      C[(size_t)row * N + col] = v;                                               \
    }                                                                             \
  }

// seg head GEMM + fused transpose side-write (dense A).
__global__ __launch_bounds__(256) void gemm_seg_kernel(const float* __restrict__ A,
                                                       const float* __restrict__ Wm,
                                                       const float* __restrict__ bias,
                                                       float* __restrict__ C,
                                                       float* __restrict__ T,
                                                       int Mrows, int N, int K) {
  GEMM_SHARED
  const int kLo = 0, kHi = K;
  const int RELU = 0;
  int rowBase = blockIdx.y * 64;
  int colBase = blockIdx.x * 64;
  const int rowA = rowBase + ((int)threadIdx.x & 63);
  const float* arow = A + (size_t)rowA * K;
  float* tbase = T + ((size_t)(rowA >> 12) * 128) * 4096 + (rowA & 4095);
  GEMM_MAIN(
    va = *reinterpret_cast<const float4*>(&arow[kq0]);
    {
      float* tp = tbase + (size_t)kq0 * 4096;
      tp[0] = va.x; tp[4096] = va.y; tp[8192] = va.z; tp[12288] = va.w;
    }
  )
  GEMM_EPI_STORE
}

// SA GEMM (SA2-4): fused grouping gather + ReLU + maxpool-over-20 via atomic-max.
__global__ __launch_bounds__(256) void gemm_sa_kernel(
    const float* __restrict__ xyz, const float* __restrict__ feats,
    const float* __restrict__ new_xyz, const int* __restrict__ nidx,
    const float* __restrict__ Wm, const float* __restrict__ bias,
    float* __restrict__ fOut, int Mref, int LDR, int S, int LDQ, int Cf,
    int Mrows, int N, int K) {
  GEMM_SHARED
  const int kLo = 0, kHi = K;
  int rowBase = blockIdx.y * 64;
  int colBase = blockIdx.x * 64;
  const int rowA = rowBase + ((int)threadIdx.x & 63);
  const int bsA = rowA / 20;
  const int sA = bsA % S;
  const int bA = bsA / S;
  const int idA = nidx[rowA];
  const float* xrA = xyz + ((size_t)bA * LDR + idA) * 3;
  const float* xqA = new_xyz + ((size_t)bA * LDQ + sA) * 3;
  const float* fbA = feats + ((size_t)bA * Mref + idA) * Cf;
  GEMM_MAIN(
    float* vp_ = (float*)&va;
    _Pragma("unroll")
    for (int c_ = 0; c_ < 4; ++c_) {
      int kq = kq0 + c_;
      float v = 0.0f;
      if (kq < K) v = (kq < 3) ? (xrA[kq] - xqA[kq]) : fbA[kq - 3];
      vp_[c_] = v;
    }
  )
  __shared__ int smax[4][64];
  int gBase = rowBase / 20;
  int nG = (rowBase + 63) / 20 - gBase + 1;
  for (int l = threadIdx.x; l < nG * 64; l += 256) smax[l >> 6][l & 63] = 0;
  __syncthreads();
  {
    int gl = (rowBase + ty * 4) / 20 - gBase;
#pragma unroll
    for (int j = 0; j < 4; ++j) {
      int col = colBase + tx * 4 + j;
      if (col >= N) continue;
      float bb = bias[col];
      float m = 0.0f;
#pragma unroll
      for (int i = 0; i < 4; ++i) {
        int row = rowBase + ty * 4 + i;
        if (row >= Mrows) continue;
        m = fmaxf(m, fmaxf(acc[i][j] + bb, 0.0f));
      }
      atomicMax(&smax[gl][tx * 4 + j], __float_as_int(m));
    }
  }
  __syncthreads();
  for (int l = threadIdx.x; l < nG * 64; l += 256) {
    int g = gBase + (l >> 6), c = colBase + (l & 63);
    if (c < N) atomicMax((int*)&fOut[(size_t)g * N + c], smax[l >> 6][l & 63]);
  }
}

// ---------------- dense GEMM (A materialized; optional cls/xyz/nrm tail) ----------------
__global__ __launch_bounds__(256) void gemm_dense_kernel(
    const float* __restrict__ A, int LDA, int KA,
    const float* __restrict__ cls, const float* __restrict__ xyzq,
    const float* __restrict__ nrmq,
    const float* __restrict__ Wm, const float* __restrict__ bias,
    float* __restrict__ C, int Mrows, int N, int K,
    int RELU, int SPLITK, int CHUNK, int Sq) {
  GEMM_SHARED
  const int kLo = blockIdx.z * CHUNK;
  const int kHi = min(K, kLo + CHUNK);
  int rowBase = blockIdx.y * 64;
  int colBase = blockIdx.x * 64;
  const int rowA = rowBase + ((int)threadIdx.x & 63);
  const float* arow = A + (size_t)rowA * LDA;
  const int bA = Sq ? rowA / Sq : 0;
  const float* clsA = cls ? cls + (size_t)bA * 16 : nullptr;
  const float* xyzqA = xyzq ? xyzq + (size_t)rowA * 3 : nullptr;
  const float* nrmqA = nrmq ? nrmq + (size_t)rowA * 3 : nullptr;
  GEMM_MAIN(
    if (kq0 + 3 < KA) {
      va = *reinterpret_cast<const float4*>(&arow[kq0]);
    } else {
      float* vp_ = (float*)&va;
      _Pragma("unroll")
      for (int c_ = 0; c_ < 4; ++c_) {
        int kq = kq0 + c_;
        float v = 0.0f;
        if (kq < KA) {
          v = arow[kq];
        } else if (kq < K) {
          int cc = kq - KA;
          if (cc < 16) v = clsA[cc];
          else if (cc < 19) v = xyzqA[cc - 16];
          else v = nrmqA[cc - 19];
        }
        vp_[c_] = v;
      }
    }
  )
  if (SPLITK) {
#pragma unroll
    for (int i = 0; i < 4; ++i) {
      int row = rowBase + ty * 4 + i;
      if (row >= Mrows) continue;
#pragma unroll
      for (int j = 0; j < 4; ++j) {
        int col = colBase + tx * 4 + j;
        if (col >= N) continue;
        atomicAdd(&C[(size_t)row * N + col], acc[i][j]);
      }
    }
  } else {
    GEMM_EPI_STORE
  }
}

// ---------------- host-side orchestration ----------------
static inline int cdiv(int a, int b) { return (a + b - 1) / b; }

extern "C" void kernel_launch(void* const* d_in, const int* in_sizes, int n_in,
                              void* d_out, int out_size, void* d_ws, size_t ws_size,
                              hipStream_t stream) {
  const float* x    = (const float*)d_in[0];
  const float* cls  = (const float*)d_in[1];
  const float* W0 = (const float*)d_in[2];  const float* b0 = (const float*)d_in[3];
  const float* W1 = (const float*)d_in[4];  const float* b1 = (const float*)d_in[5];
  const float* W2 = (const float*)d_in[6];  const float* b2 = (const float*)d_in[7];
  const float* W3 = (const float*)d_in[8];  const float* b3 = (const float*)d_in[9];
  const float* F3 = (const float*)d_in[10]; const float* fb3 = (const float*)d_in[11];
  const float* F2 = (const float*)d_in[12]; const float* fb2 = (const float*)d_in[13];
  const float* F1 = (const float*)d_in[14]; const float* fb1 = (const float*)d_in[15];
  const float* F0 = (const float*)d_in[16]; const float* fb0 = (const float*)d_in[17];
  const float* Wseg = (const float*)d_in[18]; const float* bseg = (const float*)d_in[19];
  float* out = (float*)d_out;

  float* ws = (float*)d_ws;
  size_t off = 0;
  auto alloc = [&](size_t n) { float* p = ws + off; off += (n + 3) & ~(size_t)3; return p; };
  float* xyz = alloc(8 * 4096 * 3);
  float* nrm = alloc(8 * 4096 * 3);
  float4* xyz4 = (float4*)alloc(8 * 4096 * 4);   // (x,y,z,|p|^2) for knn20
  float* x1 = alloc(8 * 512 * 3);          // x2/x3/x4 are per-batch PREFIXES of x1
  float* f1 = alloc(8 * 512 * 64);         // direct-stored by knn20
  float* f2 = alloc(8 * 256 * 128);        // f2..f4,g3,g2,g1 contiguous: one memset
  float* f3 = alloc(8 * 128 * 256);
  float* f4 = alloc(8 * 64 * 512);
  float* g3 = alloc(8 * 128 * 512);        // split-K raw accum (finalized by interp2)
  float* g2 = alloc(8 * 256 * 256);        // split-K raw accum (finalized by interp1)
  float* g1 = alloc(8 * 512 * 128);        // split-K raw accum (finalized by interp0)
  float* g0 = alloc(8 * 4096 * 128);
  float* Abuf = alloc((size_t)8 * 4096 * 128);   // time-multiplexed dense-A buffer
  int* nidx2 = (int*)alloc(8 * 256 * 20);
  int* nidx3 = (int*)alloc(8 * 128 * 20);
  int* nidx4 = (int*)alloc(8 * 64 * 20);
  int* idx3_3 = (int*)alloc(8 * 128 * 3);  float* w3_3 = alloc(8 * 128 * 3);
  int* idx3_2 = (int*)alloc(8 * 256 * 3);  float* w3_2 = alloc(8 * 256 * 3);
  int* idx3_1 = (int*)alloc(8 * 512 * 3);  float* w3_1 = alloc(8 * 512 * 3);
  int* idx3_0 = (int*)alloc(8 * 4096 * 3); float* w3_0 = alloc(8 * 4096 * 3);

  // zero f2..f4 (atomic-max targets) + g3,g2,g1 (split-K atomicAdd targets).
  hipMemsetAsync(f2, 0,
                 ((size_t)8 * (256 * 128 + 128 * 256 + 64 * 512) +
                  (size_t)8 * (128 * 512 + 256 * 256 + 512 * 128)) * 4, stream);

  fps4_kernel<256, 16><<<8, 256, 0, stream>>>(x, xyz, nrm, xyz4, 4096, 512, x1);
  // knn20 R14: 4 queries per 256-thread block (1024 blocks)
  knn20_kernel<<<8 * 512 / 4, 256, 0, stream>>>(x1, xyz4, nrm, W0, b0, f1);
  neighbors_kernel<<<1052, 256, 0, stream>>>(xyz, x1, nidx2, nidx3, nidx4,
                                             idx3_3, w3_3, idx3_2, w3_2,
                                             idx3_1, w3_1, idx3_0, w3_0);

  // ---- SA2: Cin 67 -> 128 ----
  {
    dim3 grid(2, cdiv(8 * 256 * 20, 64));
    gemm_sa_kernel<<<grid, 256, 0, stream>>>(x1, f1, x1, nidx2, W1, b1, f2,
                                             512, 512, 256, 512, 64,
                                             8 * 256 * 20, 128, 67);
  }
  // ---- SA3: Cin 131 -> 256 ----
  {
    dim3 grid(4, cdiv(8 * 128 * 20, 64));
    gemm_sa_kernel<<<grid, 256, 0, stream>>>(x1, f2, x1, nidx3, W2, b2, f3,
                                             256, 512, 128, 512, 128,
                                             8 * 128 * 20, 256, 131);
  }
  // ---- SA4: Cin 259 -> 512 ----
  {
    dim3 grid(8, cdiv(8 * 64 * 20, 64));
    gemm_sa_kernel<<<grid, 256, 0, stream>>>(x1, f3, x1, nidx4, W3, b3, f4,
                                             128, 512, 64, 512, 256,
                                             8 * 64 * 20, 512, 259);
  }

  // ---- FP3: interp -> dense A (1024x768); GEMM splitK x4 ----
  interp_kernel<<<8 * 128 / 4, 256, 0, stream>>>(f4, idx3_3, w3_3, f3, nullptr,
                                                 Abuf, 128, 64, 512, 256, 768);
  {
    dim3 grid(8, cdiv(8 * 128, 64), 4);
    gemm_dense_kernel<<<grid, 256, 0, stream>>>(Abuf, 768, 768,
                                                nullptr, nullptr, nullptr,
                                                F3, fb3, g3, 8 * 128, 512, 768,
                                                0, 1, 192, 0);
  }
  // ---- FP2: interp (g3 raw + fb3 finalize + skip f2) -> A (2048x640); splitK x4 ----
  interp_kernel<<<8 * 256 / 4, 256, 0, stream>>>(g3, idx3_2, w3_2, f2, fb3,
                                                 Abuf, 256, 128, 512, 128, 640);
  {
    dim3 grid(4, cdiv(8 * 256, 64), 4);
    gemm_dense_kernel<<<grid, 256, 0, stream>>>(Abuf, 640, 640,
                                                nullptr, nullptr, nullptr,
                                                F2, fb2, g2, 8 * 256, 256, 640,
                                                0, 1, 160, 0);
  }
  // ---- FP1: interp (g2 raw + fb2 + skip f1) -> A (4096x320); splitK x2 ----
  interp_kernel<<<8 * 512 / 4, 256, 0, stream>>>(g2, idx3_1, w3_1, f1, fb2,
                                                 Abuf, 512, 256, 256, 64, 320);
  {
    dim3 grid(2, cdiv(8 * 512, 64), 2);
    gemm_dense_kernel<<<grid, 256, 0, stream>>>(Abuf, 320, 320,
                                                nullptr, nullptr, nullptr,
                                                F1, fb1, g1, 8 * 512, 128, 320,
                                                0, 1, 160, 0);
  }
  // ---- FP0: interp (g1 raw + fb1, 128ch) -> A (32768x128); GEMM + tail K=150 ----
  interp_kernel<<<8 * 4096 / 4, 256, 0, stream>>>(g1, idx3_0, w3_0, nullptr, fb1,
                                                  Abuf, 4096, 512, 128, 0, 128);
  {
    dim3 grid(2, cdiv(8 * 4096, 64), 1);
    gemm_dense_kernel<<<grid, 256, 0, stream>>>(Abuf, 128, 128,
                                                cls, xyz, nrm,
                                                F0, fb0, g0, 8 * 4096, 128, 150,
                                                1, 0, 160, 4096);
  }

  // ---- seg head + fused transpose ----
  {
    dim3 grid(1, cdiv(8 * 4096, 64));
    gemm_seg_kernel<<<grid, 256, 0, stream>>>(g0, Wseg, bseg, out,
                                              out + (size_t)8 * 4096 * 50,
                                              8 * 4096, 50, 128);
  }
}

// Round 15
// 909.001 us; speedup vs baseline: 3.5364x; 1.0033x over previous
//
#include <hip/hip_runtime.h>
#include <float.h>

#define B8 8
#define NPTS 4096

// ---------------- DPP helpers ----------------
template <int CTRL, int RM>
__device__ __forceinline__ unsigned dppmov(unsigned v) {
  return (unsigned)__builtin_amdgcn_update_dpp((int)v, (int)v, CTRL, RM, 0xf, false);
}

template <int CTRL, int RM>
__device__ __forceinline__ void red_key_max(unsigned& kh, unsigned& kl) {
  unsigned oh = dppmov<CTRL, RM>(kh);
  unsigned ol = dppmov<CTRL, RM>(kl);
  unsigned long long ko = ((unsigned long long)oh << 32) | ol;
  unsigned long long k  = ((unsigned long long)kh << 32) | kl;
  bool c = ko > k;
  kh = c ? oh : kh;
  kl = c ? ol : kl;
}

template <int CTRL, int RM>
__device__ __forceinline__ void red_key_min(unsigned& kh, unsigned& kl) {
  unsigned oh = dppmov<CTRL, RM>(kh);
  unsigned ol = dppmov<CTRL, RM>(kl);
  unsigned long long ko = ((unsigned long long)oh << 32) | ol;
  unsigned long long k  = ((unsigned long long)kh << 32) | kl;
  bool c = ko < k;
  kh = c ? oh : kh;
  kl = c ? ol : kl;
}

#define WAVE_RED_MAX(kh, kl)            \
  red_key_max<0x111, 0xf>(kh, kl);      \
  red_key_max<0x112, 0xf>(kh, kl);      \
  red_key_max<0x114, 0xf>(kh, kl);      \
  red_key_max<0x118, 0xf>(kh, kl);      \
  red_key_max<0x142, 0xa>(kh, kl);      \
  red_key_max<0x143, 0xc>(kh, kl);

#define WAVE_RED_MIN(kh, kl)            \
  red_key_min<0x111, 0xf>(kh, kl);      \
  red_key_min<0x112, 0xf>(kh, kl);      \
  red_key_min<0x114, 0xf>(kh, kl);      \
  red_key_min<0x118, 0xf>(kh, kl);      \
  red_key_min<0x142, 0xa>(kh, kl);      \
  red_key_min<0x143, 0xc>(kh, kl);

// ---------------- FPS + fused split (closed at ~324us) ----------------
template <int BLOCK, int P>
__global__ __launch_bounds__(BLOCK) void fps4_kernel(const float* __restrict__ x,
                                                     float* __restrict__ xyz,
                                                     float* __restrict__ nrm,
                                                     float4* __restrict__ xyz4,
                                                     int N, int S,
                                                     float* __restrict__ out_xyz) {
#pragma clang fp contract(off)
  constexpr int NW = BLOCK / 64;
  __shared__ float4 pts[BLOCK * P];
  __shared__ float4 sel[512];
  __shared__ alignas(16) unsigned long long wkey[2][NW];
  int b = blockIdx.x, t = threadIdx.x;
  const float* xb = x + (size_t)b * 6 * N;
  float px[P], py[P], pz[P], dist[P];
#pragma unroll
  for (int j = 0; j < P; ++j) {
    int idx = t + j * BLOCK;
    float a = xb[0 * N + idx], bb = xb[1 * N + idx], c = xb[2 * N + idx];
    px[j] = a; py[j] = bb; pz[j] = c;
    pts[idx] = make_float4(a, bb, c, 0.f);
    dist[j] = 1e10f;
    size_t g = (size_t)b * N + idx;
    float* o1 = xyz + g * 3;
    o1[0] = a; o1[1] = bb; o1[2] = c;
    xyz4[g] = make_float4(a, bb, c, a * a + bb * bb + c * c);
    float n0 = xb[3 * N + idx], n1 = xb[4 * N + idx], n2 = xb[5 * N + idx];
    float* o2 = nrm + g * 3;
    o2[0] = n0; o2[1] = n1; o2[2] = n2;
  }
  __syncthreads();
  float fx = xb[0], fy = xb[N], fz = xb[2 * N];
  for (int i = 0; i < S; ++i) {
    if (t == 0) sel[i] = make_float4(fx, fy, fz, 0.f);
    float bv = -1.0f;
    int bj = 0;
#pragma unroll
    for (int j = 0; j < P; ++j) {
      float dx = px[j] - fx, dy = py[j] - fy, dz = pz[j] - fz;
      float d = dx * dx + dy * dy + dz * dz;
      float nd = fminf(dist[j], d);
      dist[j] = nd;
      bool c = nd > bv;
      bv = c ? nd : bv;
      bj = c ? j : bj;
    }
    unsigned kh = __float_as_uint(bv);
    unsigned kl = (unsigned)(~(t + bj * BLOCK));
    WAVE_RED_MAX(kh, kl);
    int buf = i & 1;
    if ((t & 63) == 63)
      wkey[buf][t >> 6] = ((unsigned long long)kh << 32) | kl;
    __syncthreads();
    unsigned long long g = 0ull;
    const ulonglong2* wk2 = (const ulonglong2*)&wkey[buf][0];
#pragma unroll
    for (int w = 0; w < NW / 2; ++w) {
      ulonglong2 e = wk2[w];
      unsigned long long m = (e.x > e.y) ? e.x : e.y;
      g = (m > g) ? m : g;
    }
    int far = (int)~(unsigned)g;
    float4 f = pts[far];
    fx = f.x; fy = f.y; fz = f.z;
  }
  __syncthreads();
  for (int i = t; i < S; i += BLOCK) {
    float4 f = sel[i];
    float* o = out_xyz + ((size_t)b * S + i) * 3;
    o[0] = f.x; o[1] = f.y; o[2] = f.z;
  }
}

// ---------------- kNN k=20 + fused SA1 (registerized, 4 waves/block) ----------------
__global__ __launch_bounds__(256) void knn20_kernel(const float* __restrict__ q,
                                                    const float4* __restrict__ ref4,
                                                    const float* __restrict__ nrm,
                                                    const float* __restrict__ W,
                                                    const float* __restrict__ bias,
                                                    float* __restrict__ f1) {
#pragma clang fp contract(off)
  int wv = (int)threadIdx.x >> 6, t = (int)threadIdx.x & 63;
  int bs = blockIdx.x * 4 + wv;        // b*512 + s  (== group id)
  int b = bs >> 9;
  __shared__ alignas(16) float smem_in[4][20][8];
  const float* qp = q + (size_t)bs * 3;
  float qx = qp[0], qy = qp[1], qz = qp[2];
  float qq = qx * qx + qy * qy + qz * qz;
  const float4* rp = ref4 + (size_t)b * 4096;
  float v1 = FLT_MAX, v2 = FLT_MAX;
  int i1 = 0, i2 = 0;
  for (int k = 0; k < 64; ++k) {
    int i = t + (k << 6);
    float4 r = rp[i];
    float dot = qx * r.x + qy * r.y + qz * r.z;
    float d = qq - 2.0f * dot + r.w;
    if (d < v1) { v2 = v1; i2 = i1; v1 = d; i1 = i; }
    else if (d < v2) { v2 = d; i2 = i; }
  }
  unsigned long long taken = 0ull;
  unsigned keep = 0;
  for (int k = 0; k < 20; ++k) {
    unsigned kh = __float_as_uint(v1), kl = (unsigned)i1;
    WAVE_RED_MIN(kh, kl);
    unsigned w = (unsigned)__builtin_amdgcn_readlane((int)kl, 63);
    if (t == k) keep = w;
    if (((int)w & 63) == t) {          // I owned the winner (w == my i1)
      taken |= 1ull << ((int)w >> 6);
      v1 = v2; i1 = i2;
      v2 = FLT_MAX; i2 = 0;
      if (v1 == FLT_MAX) {             // cache exhausted (rare): recompute scan
        for (int j = 0; j < 64; ++j) {
          if ((taken >> j) & 1ull) continue;
          int i = t + (j << 6);
          float4 r = rp[i];
          float dot = qx * r.x + qy * r.y + qz * r.z;
          float d = qq - 2.0f * dot + r.w;
          if (d < v1) { v2 = v1; i2 = i1; v1 = d; i1 = i; }
          else if (d < v2) { v2 = d; i2 = i; }
        }
      }
    }
  }
  if (t < 20) {
    int id = (int)keep;
    float4 r = rp[id];                 // (x,y,z,|p|^2)
    const float* nr = nrm + ((size_t)b * 4096 + id) * 3;
    smem_in[wv][t][0] = r.x - qx;
    smem_in[wv][t][1] = r.y - qy;
    smem_in[wv][t][2] = r.z - qz;
    smem_in[wv][t][3] = nr[0];
    smem_in[wv][t][4] = nr[1];
    smem_in[wv][t][5] = nr[2];
    smem_in[wv][t][6] = 0.0f;
    smem_in[wv][t][7] = 0.0f;
  }
  __syncthreads();                     // uniform single barrier (4 waves)
  float w0 = W[0 * 64 + t], w1 = W[1 * 64 + t], w2 = W[2 * 64 + t];
  float w3 = W[3 * 64 + t], w4 = W[4 * 64 + t], w5 = W[5 * 64 + t];
  float bb = bias[t];
  float m = 0.0f;                      // relu >= 0: 0-init absorbs the relu clamp
  for (int n = 0; n < 20; ++n) {
    const float4 a = *reinterpret_cast<const float4*>(&smem_in[wv][n][0]);
    const float4 c = *reinterpret_cast<const float4*>(&smem_in[wv][n][4]);
    float v = a.x * w0;
    v += a.y * w1;
    v += a.z * w2;
    v += a.w * w3;
    v += c.x * w4;
    v += c.y * w5;
    v += bb;
    m = fmaxf(m, v);
  }
  f1[(size_t)bs * 64 + t] = m;
}

// ---------------- knn3 select+store helper ----------------
__device__ __forceinline__ void knn3_store(int g, const float* rx3,
                                           float qx, float qy, float qz,
                                           int i0, int i1, int i2,
                                           int* __restrict__ idx3,
                                           float* __restrict__ w3) {
#pragma clang fp contract(off)
  int ii[3] = {i0, i1, i2};
  float w[3];
  float wsum = 0.0f;
#pragma unroll
  for (int k = 0; k < 3; ++k) {
    const float* r = rx3 + (size_t)ii[k] * 3;
    float dx = r[0] - qx, dy = r[1] - qy, dz = r[2] - qz;
    float d = dx * dx + dy * dy + dz * dz;
    w[k] = 1.0f / (d + 1e-8f);
    wsum += w[k];
  }
#pragma unroll
  for (int k = 0; k < 3; ++k) {
    idx3[(size_t)g * 3 + k] = ii[k];
    w3[(size_t)g * 3 + k] = w[k] / wsum;
  }
}

// ---------------- fused neighbor kernel: SA2/3/4 knn20 + all knn3 ----------------
__global__ __launch_bounds__(256) void neighbors_kernel(
    const float* __restrict__ xyz, const float* __restrict__ x1,
    int* __restrict__ nidx2, int* __restrict__ nidx3, int* __restrict__ nidx4,
    int* __restrict__ idx3_3, float* __restrict__ w3_3,
    int* __restrict__ idx3_2, float* __restrict__ w3_2,
    int* __restrict__ idx3_1, float* __restrict__ w3_1,
    int* __restrict__ idx3_0, float* __restrict__ w3_0) {
#pragma clang fp contract(off)
  __shared__ float4 smem4[512];          // 8 KB, aliased per region
  int blk = blockIdx.x, tid = threadIdx.x;

  if (blk < 896) {  // ---- knn20 regions ----
    int S, M, qid;
    int* nout;
    const int wv = tid >> 6, t64 = tid & 63;
    if (blk < 512)      { S = 256; M = 512; qid = blk * 4 + wv;         nout = nidx2; }
    else if (blk < 768) { S = 128; M = 256; qid = (blk - 512) * 4 + wv; nout = nidx3; }
    else                { S = 64;  M = 128; qid = (blk - 768) * 4 + wv; nout = nidx4; }
    float* swd = (float*)smem4 + wv * M;
    int b = qid / S, s = qid % S;
    const float* qp = x1 + ((size_t)b * 512 + s) * 3;
    float qx = qp[0], qy = qp[1], qz = qp[2];
    float qq = qx * qx + qy * qy + qz * qz;
    const float* rp = x1 + (size_t)b * 512 * 3;
    for (int i = t64; i < M; i += 64) {
      float rx = rp[3 * i], ry = rp[3 * i + 1], rz = rp[3 * i + 2];
      float rr = rx * rx + ry * ry + rz * rz;
      float dot = qx * rx + qy * ry + qz * rz;
      swd[i] = qq - 2.0f * dot + rr;
    }
    __syncthreads();
    unsigned keep = 0;
    for (int k = 0; k < 20; ++k) {
      float bv = FLT_MAX;
      int bi = 0;
      for (int i = t64; i < M; i += 64) {
        float v = swd[i];
        bool c = v < bv;
        bv = c ? v : bv;
        bi = c ? i : bi;
      }
      unsigned kh = __float_as_uint(bv), kl = (unsigned)bi;
      WAVE_RED_MIN(kh, kl);
      unsigned w = (unsigned)__builtin_amdgcn_readlane((int)kl, 63);
      if (t64 == k) keep = w;
      if (t64 == 0) swd[w] = FLT_MAX;
      __syncthreads();   // uniform across the block's 4 waves (same trip count)
    }
    if (t64 < 20) nout[(size_t)qid * 20 + t64] = (int)keep;
    return;
  }

  if (blk < 900) {  // ---- FP3 knn3, plain VMEM scan (M=64) ----
    int g = (blk - 896) * 256 + tid;     // < 1024
    int Sq = 128, M = 64;
    int b = g / Sq, s = g % Sq;
    const float* qp = x1 + ((size_t)b * 512 + s) * 3;
    float qx = qp[0], qy = qp[1], qz = qp[2];
    float qq = qx * qx + qy * qy + qz * qz;
    const float* rp = x1 + (size_t)b * 512 * 3;
    float v0 = FLT_MAX, v1 = FLT_MAX, v2 = FLT_MAX;
    int i0 = 0, i1 = 0, i2 = 0;
    for (int i = 0; i < M; ++i) {
      float rx = rp[3 * i], ry = rp[3 * i + 1], rz = rp[3 * i + 2];
      float d = qq - 2.0f * (qx * rx + qy * ry + qz * rz) + (rx * rx + ry * ry + rz * rz);
      if (d < v2) {
        if (d < v1) {
          if (d < v0) { v2 = v1; i2 = i1; v1 = v0; i1 = i0; v0 = d; i0 = i; }
          else { v2 = v1; i2 = i1; v1 = d; i1 = i; }
        } else { v2 = d; i2 = i; }
      }
    }
    knn3_store(g, rp, qx, qy, qz, i0, i1, i2, idx3_3, w3_3);
    return;
  }

  // ---- knn3 LDS regions (block-uniform batch) ----
  int g, Sq, M, LDQ;
  int* oidx;
  float* ow;
  const float* q;
  if (blk < 908)      { g = (blk - 900) * 256 + tid; Sq = 256;  M = 128; oidx = idx3_2; ow = w3_2; q = x1;  LDQ = 512; }
  else if (blk < 924) { g = (blk - 908) * 256 + tid; Sq = 512;  M = 256; oidx = idx3_1; ow = w3_1; q = x1;  LDQ = 512; }
  else                { g = (blk - 924) * 256 + tid; Sq = 4096; M = 512; oidx = idx3_0; ow = w3_0; q = xyz; LDQ = 4096; }
  int b = g / Sq, s = g % Sq;
  const float* rp = x1 + (size_t)b * 512 * 3;
  for (int i = tid; i < M; i += 256) {
    float rx = rp[3 * i], ry = rp[3 * i + 1], rz = rp[3 * i + 2];
    smem4[i] = make_float4(rx, ry, rz, rx * rx + ry * ry + rz * rz);
  }
  __syncthreads();
  const float* qp = q + ((size_t)b * LDQ + s) * 3;
  float qx = qp[0], qy = qp[1], qz = qp[2];
  float qq = qx * qx + qy * qy + qz * qz;
  float v0 = FLT_MAX, v1 = FLT_MAX, v2 = FLT_MAX;
  int i0 = 0, i1 = 0, i2 = 0;
  for (int i = 0; i < M; ++i) {
    float4 r = smem4[i];
    float d = qq - 2.0f * (qx * r.x + qy * r.y + qz * r.z) + r.w;
    if (d < v2) {
      if (d < v1) {
        if (d < v0) { v2 = v1; i2 = i1; v1 = v0; i1 = i0; v0 = d; i0 = i; }
        else { v2 = v1; i2 = i1; v1 = d; i1 = i; }
      } else { v2 = d; i2 = i; }
    }
  }
  {
    int ii[3] = {i0, i1, i2};
    float w[3];
    float wsum = 0.0f;
#pragma unroll
    for (int k = 0; k < 3; ++k) {
      float4 r = smem4[ii[k]];
      float dx = r.x - qx, dy = r.y - qy, dz = r.z - qz;
      float d = dx * dx + dy * dy + dz * dz;
      w[k] = 1.0f / (d + 1e-8f);
      wsum += w[k];
    }
#pragma unroll
    for (int k = 0; k < 3; ++k) {
      oidx[(size_t)g * 3 + k] = ii[k];
      ow[(size_t)g * 3 + k] = w[k] / wsum;
    }
  }
}

// ---------------- interp kernel: materialize dense A rows (FP layers) ----------------
__global__ __launch_bounds__(256) void interp_kernel(
    const float* __restrict__ fr, const int* __restrict__ idx3,
    const float* __restrict__ w3, const float* __restrict__ skip,
    const float* __restrict__ frBias,
    float* __restrict__ A, int Sq, int Mr, int Cr, int Cs, int LDA) {
#pragma clang fp contract(off)
  int row = blockIdx.x * 4 + ((int)threadIdx.x >> 6);
  int t = (int)threadIdx.x & 63;
  int b = row / Sq;
  const int* ii = idx3 + (size_t)row * 3;
  const float* ww = w3 + (size_t)row * 3;
  const float* fb = fr + (size_t)b * Mr * Cr;
  const float* f0 = fb + (size_t)ii[0] * Cr;
  const float* f1 = fb + (size_t)ii[1] * Cr;
  const float* f2 = fb + (size_t)ii[2] * Cr;
  float w0 = ww[0], w1 = ww[1], w2 = ww[2];
  float* arow = A + (size_t)row * LDA;
  for (int kq = t; kq < Cr; kq += 64) {
    float a0 = f0[kq], a1 = f1[kq], a2 = f2[kq];
    if (frBias) {
      float bb = frBias[kq];
      a0 = fmaxf(a0 + bb, 0.0f);
      a1 = fmaxf(a1 + bb, 0.0f);
      a2 = fmaxf(a2 + bb, 0.0f);
    }
    float v = w0 * a0;
    v += w1 * a1;
    v += w2 * a2;
    arow[kq] = v;
  }
  if (skip) {
    const float* sk = skip + (size_t)row * Cs;
    for (int kq = t; kq < Cs; kq += 64) arow[Cr + kq] = sk[kq];
  }
}

// ---------------- R15 gather kernel: materialize dense SA A rows ----------------
// One wave per grouped row (bs*20+n): lane-per-channel coalesced read of the
// neighbor's feature row + rel-xyz head. Same per-element expression as the
// old fused stage -> bitwise identical. Pads [K, LDA) written 0.
__global__ __launch_bounds__(256) void gather_sa_kernel(
    const float* __restrict__ xyz, const float* __restrict__ feats,
    const float* __restrict__ new_xyz, const int* __restrict__ nidx,
    float* __restrict__ A,
    int Mref, int LDR, int S, int LDQ, int Cf, int LDA) {
#pragma clang fp contract(off)
  int row = blockIdx.x * 4 + ((int)threadIdx.x >> 6);
  int t = (int)threadIdx.x & 63;
  int bs = row / 20;
  int s = bs % S;
  int b = bs / S;
  int id = nidx[row];
  const float* xr = xyz + ((size_t)b * LDR + id) * 3;
  const float* xq = new_xyz + ((size_t)b * LDQ + s) * 3;
  const float* fb = feats + ((size_t)b * Mref + id) * Cf;
  float* ar = A + (size_t)row * LDA;
  int K = Cf + 3;
  for (int kq = t; kq < LDA; kq += 64) {
    float v = 0.0f;
    if (kq < 3) v = xr[kq] - xq[kq];
    else if (kq < K) v = fb[kq - 3];
    ar[kq] = v;
  }
}

// ---------------- double-buffered GEMM core (R6: 64x64, BK=16, row-quad) ----------------
#define GEMM_SHARED                                                               \
  __shared__ alignas(16) float As[2][16][68];                                     \
  __shared__ alignas(16) float Bs[2][16][64];

#define GEMM_STAGE(k0v, ...)                                                      \
    {                                                                             \
      int kq0 = (k0v) + (((int)threadIdx.x >> 6) << 2);                           \
      float4 va = make_float4(0.f, 0.f, 0.f, 0.f);                                \
      { __VA_ARGS__ }                                                             \
      areg4 = va;                                                                 \
    }                                                                             \
    {                                                                             \
      int kk = (int)threadIdx.x >> 4;                                             \
      int n4 = ((int)threadIdx.x & 15) * 4;                                       \
      int kq = (k0v) + kk, cc = colBase + n4;                                     \
      if (colBase + 64 <= N) {                                                    \
        if (kq < K) breg4 = *reinterpret_cast<const float4*>(&Wm[(size_t)kq * N + cc]); \
        else breg4 = make_float4(0.f, 0.f, 0.f, 0.f);                             \
      } else {                                                                    \
        breg4.x = (kq < K && cc < N) ? Wm[(size_t)kq * N + cc] : 0.0f;            \
        breg4.y = (kq < K && cc + 1 < N) ? Wm[(size_t)kq * N + cc + 1] : 0.0f;    \
        breg4.z = (kq < K && cc + 2 < N) ? Wm[(size_t)kq * N + cc + 2] : 0.0f;    \
        breg4.w = (kq < K && cc + 3 < N) ? Wm[(size_t)kq * N + cc + 3] : 0.0f;    \
      }                                                                           \
    }

#define GEMM_WRITE_LDS(bufv)                                                      \
    {                                                                             \
      int r_ = (int)threadIdx.x & 63;                                             \
      int k4_ = ((int)threadIdx.x >> 6) * 4;                                      \
      As[bufv][k4_ + 0][r_] = areg4.x;                                            \
      As[bufv][k4_ + 1][r_] = areg4.y;                                            \
      As[bufv][k4_ + 2][r_] = areg4.z;                                            \
      As[bufv][k4_ + 3][r_] = areg4.w;                                            \
    }                                                                             \
    *reinterpret_cast<float4*>(&Bs[bufv][threadIdx.x >> 4][(threadIdx.x & 15) * 4]) = breg4;

#define GEMM_MAIN(...)                                                            \
  int tx = threadIdx.x & 15, ty = threadIdx.x >> 4;                               \
  float acc[4][4] = {};                                                           \
  float4 areg4, breg4;                                                            \
  GEMM_STAGE(kLo, __VA_ARGS__)                                                    \
  GEMM_WRITE_LDS(0)                                                               \
  __syncthreads();                                                                \
  int cur = 0;                                                                    \
  for (int k0 = kLo; k0 < kHi; k0 += 16) {                                        \
    int nxt = cur ^ 1;                                                            \
    bool more = (k0 + 16 < kHi);                                                  \
    if (more) { GEMM_STAGE(k0 + 16, __VA_ARGS__) }                                \
    _Pragma("unroll")                                                             \
    for (int kk = 0; kk < 16; ++kk) {                                             \
      const float4 av = *reinterpret_cast<const float4*>(&As[cur][kk][ty * 4]);   \
      const float4 bv = *reinterpret_cast<const float4*>(&Bs[cur][kk][tx * 4]);   \
      acc[0][0] += av.x * bv.x; acc[0][1] += av.x * bv.y;                         \
      acc[0][2] += av.x * bv.z; acc[0][3] += av.x * bv.w;                         \
      acc[1][0] += av.y * bv.x; acc[1][1] += av.y * bv.y;                         \
      acc[1][2] += av.y * bv.z; acc[1][3] += av.y * bv.w;                         \
      acc[2][0] += av.z * bv.x; acc[2][1] += av.z * bv.y;                         \
      acc[2][2] += av.z * bv.z; acc[2][3] += av.z * bv.w;                         \
      acc[3][0] += av.w * bv.x; acc[3][1] += av.w * bv.y;                         \
      acc[3][2] += av.w * bv.z; acc[3][3] += av.w * bv.w;                         \
    }                                                                             \
    if (more) { GEMM_WRITE_LDS(nxt) }                                             \
    __syncthreads();                                                              \
    cur = nxt;                                                                    \
  }

#define GEMM_EPI_STORE                                                            \
  _Pragma("unroll")                                                               \
  for (int i = 0; i < 4; ++i) {                                                   \
    int row = rowBase + ty * 4 + i;                                               \
    if (row >= Mrows) continue;                                                   \
    _Pragma("unroll")                                                             \
    for (int j = 0; j < 4; ++j) {                                                 \
      int col = colBase + tx * 4 + j;                                             \
      if (col >= N) continue;                                                     \
      float v = acc[i][j] + bias[col];                                            \
      if (RELU) v = fmaxf(v, 0.0f);                                               \
      C[(size_t)row * N + col] = v;                                               \
    }                                                                             \
  }

// seg head GEMM + fused transpose side-write (dense A).
__global__ __launch_bounds__(256) void gemm_seg_kernel(const float* __restrict__ A,
                                                       const float* __restrict__ Wm,
                                                       const float* __restrict__ bias,
                                                       float* __restrict__ C,
                                                       float* __restrict__ T,
                                                       int Mrows, int N, int K) {
  GEMM_SHARED
  const int kLo = 0, kHi = K;
  const int RELU = 0;
  int rowBase = blockIdx.y * 64;
  int colBase = blockIdx.x * 64;
  const int rowA = rowBase + ((int)threadIdx.x & 63);
  const float* arow = A + (size_t)rowA * K;
  float* tbase = T + ((size_t)(rowA >> 12) * 128) * 4096 + (rowA & 4095);
  GEMM_MAIN(
    va = *reinterpret_cast<const float4*>(&arow[kq0]);
    {
      float* tp = tbase + (size_t)kq0 * 4096;
      tp[0] = va.x; tp[4096] = va.y; tp[8192] = va.z; tp[12288] = va.w;
    }
  )
  GEMM_EPI_STORE
}

// ---------------- R15 dense SA GEMM: dense A + maxpool-over-20 epilogue ----------------
// fOut must be zero-initialized; relu >= 0 so float-bit int max == float max.
__global__ __launch_bounds__(256) void gemm_dsa_kernel(
    const float* __restrict__ A, int LDA,
    const float* __restrict__ Wm, const float* __restrict__ bias,
    float* __restrict__ fOut, int Mrows, int N, int K) {
  GEMM_SHARED
  const int kLo = 0, kHi = K;
  int rowBase = blockIdx.y * 64;
  int colBase = blockIdx.x * 64;
  const int rowA = rowBase + ((int)threadIdx.x & 63);
  const float* arow = A + (size_t)rowA * LDA;
  GEMM_MAIN(
    if (kq0 + 3 < K) {
      va = *reinterpret_cast<const float4*>(&arow[kq0]);
    } else {
      float* vp_ = (float*)&va;
      _Pragma("unroll")
      for (int c_ = 0; c_ < 4; ++c_) {
        int kq = kq0 + c_;
        vp_[c_] = (kq < K) ? arow[kq] : 0.0f;
      }
    }
  )
  __shared__ int smax[4][64];
  int gBase = rowBase / 20;
  int nG = (rowBase + 63) / 20 - gBase + 1;
  for (int l = threadIdx.x; l < nG * 64; l += 256) smax[l >> 6][l & 63] = 0;
  __syncthreads();
  {
    int gl = (rowBase + ty * 4) / 20 - gBase;
#pragma unroll
    for (int j = 0; j < 4; ++j) {
      int col = colBase + tx * 4 + j;
      if (col >= N) continue;
      float bb = bias[col];
      float m = 0.0f;
#pragma unroll
      for (int i = 0; i < 4; ++i) {
        int row = rowBase + ty * 4 + i;
        if (row >= Mrows) continue;
        m = fmaxf(m, fmaxf(acc[i][j] + bb, 0.0f));
      }
      atomicMax(&smax[gl][tx * 4 + j], __float_as_int(m));
    }
  }
  __syncthreads();
  for (int l = threadIdx.x; l < nG * 64; l += 256) {
    int g = gBase + (l >> 6), c = colBase + (l & 63);
    if (c < N) atomicMax((int*)&fOut[(size_t)g * N + c], smax[l >> 6][l & 63]);
  }
}

// ---------------- dense GEMM (FP layers; optional cls/xyz/nrm tail) ----------------
__global__ __launch_bounds__(256) void gemm_dense_kernel(
    const float* __restrict__ A, int LDA, int KA,
    const float* __restrict__ cls, const float* __restrict__ xyzq,
    const float* __restrict__ nrmq,
    const float* __restrict__ Wm, const float* __restrict__ bias,
    float* __restrict__ C, int Mrows, int N, int K,
    int RELU, int SPLITK, int CHUNK, int Sq) {
  GEMM_SHARED
  const int kLo = blockIdx.z * CHUNK;
  const int kHi = min(K, kLo + CHUNK);
  int rowBase = blockIdx.y * 64;
  int colBase = blockIdx.x * 64;
  const int rowA = rowBase + ((int)threadIdx.x & 63);
  const float* arow = A + (size_t)rowA * LDA;
  const int bA = Sq ? rowA / Sq : 0;
  const float* clsA = cls ? cls + (size_t)bA * 16 : nullptr;
  const float* xyzqA = xyzq ? xyzq + (size_t)rowA * 3 : nullptr;
  const float* nrmqA = nrmq ? nrmq + (size_t)rowA * 3 : nullptr;
  GEMM_MAIN(
    if (kq0 + 3 < KA) {
      va = *reinterpret_cast<const float4*>(&arow[kq0]);
    } else {
      float* vp_ = (float*)&va;
      _Pragma("unroll")
      for (int c_ = 0; c_ < 4; ++c_) {
        int kq = kq0 + c_;
        float v = 0.0f;
        if (kq < KA) {
          v = arow[kq];
        } else if (kq < K) {
          int cc = kq - KA;
          if (cc < 16) v = clsA[cc];
          else if (cc < 19) v = xyzqA[cc - 16];
          else v = nrmqA[cc - 19];
        }
        vp_[c_] = v;
      }
    }
  )
  if (SPLITK) {
#pragma unroll
    for (int i = 0; i < 4; ++i) {
      int row = rowBase + ty * 4 + i;
      if (row >= Mrows) continue;
#pragma unroll
      for (int j = 0; j < 4; ++j) {
        int col = colBase + tx * 4 + j;
        if (col >= N) continue;
        atomicAdd(&C[(size_t)row * N + col], acc[i][j]);
      }
    }
  } else {
    GEMM_EPI_STORE
  }
}

// ---------------- host-side orchestration ----------------
static inline int cdiv(int a, int b) { return (a + b - 1) / b; }

extern "C" void kernel_launch(void* const* d_in, const int* in_sizes, int n_in,
                              void* d_out, int out_size, void* d_ws, size_t ws_size,
                              hipStream_t stream) {
  const float* x    = (const float*)d_in[0];
  const float* cls  = (const float*)d_in[1];
  const float* W0 = (const float*)d_in[2];  const float* b0 = (const float*)d_in[3];
  const float* W1 = (const float*)d_in[4];  const float* b1 = (const float*)d_in[5];
  const float* W2 = (const float*)d_in[6];  const float* b2 = (const float*)d_in[7];
  const float* W3 = (const float*)d_in[8];  const float* b3 = (const float*)d_in[9];
  const float* F3 = (const float*)d_in[10]; const float* fb3 = (const float*)d_in[11];
  const float* F2 = (const float*)d_in[12]; const float* fb2 = (const float*)d_in[13];
  const float* F1 = (const float*)d_in[14]; const float* fb1 = (const float*)d_in[15];
  const float* F0 = (const float*)d_in[16]; const float* fb0 = (const float*)d_in[17];
  const float* Wseg = (const float*)d_in[18]; const float* bseg = (const float*)d_in[19];
  float* out = (float*)d_out;

  float* ws = (float*)d_ws;
  size_t off = 0;
  auto alloc = [&](size_t n) { float* p = ws + off; off += (n + 3) & ~(size_t)3; return p; };
  float* xyz = alloc(8 * 4096 * 3);
  float* nrm = alloc(8 * 4096 * 3);
  float4* xyz4 = (float4*)alloc(8 * 4096 * 4);   // (x,y,z,|p|^2) for knn20
  float* x1 = alloc(8 * 512 * 3);          // x2/x3/x4 are per-batch PREFIXES of x1
  float* f1 = alloc(8 * 512 * 64);         // direct-stored by knn20
  float* f2 = alloc(8 * 256 * 128);        // f2..f4,g3,g2,g1 contiguous: one memset
  float* f3 = alloc(8 * 128 * 256);
  float* f4 = alloc(8 * 64 * 512);
  float* g3 = alloc(8 * 128 * 512);        // split-K raw accum (finalized by interp2)
  float* g2 = alloc(8 * 256 * 256);        // split-K raw accum (finalized by interp1)
  float* g1 = alloc(8 * 512 * 128);        // split-K raw accum (finalized by interp0)
  float* g0 = alloc(8 * 4096 * 128);
  float* Abuf = alloc((size_t)8 * 4096 * 128);   // time-multiplexed dense-A buffer (16.8MB)
  int* nidx2 = (int*)alloc(8 * 256 * 20);
  int* nidx3 = (int*)alloc(8 * 128 * 20);
  int* nidx4 = (int*)alloc(8 * 64 * 20);
  int* idx3_3 = (int*)alloc(8 * 128 * 3);  float* w3_3 = alloc(8 * 128 * 3);
  int* idx3_2 = (int*)alloc(8 * 256 * 3);  float* w3_2 = alloc(8 * 256 * 3);
  int* idx3_1 = (int*)alloc(8 * 512 * 3);  float* w3_1 = alloc(8 * 512 * 3);
  int* idx3_0 = (int*)alloc(8 * 4096 * 3); float* w3_0 = alloc(8 * 4096 * 3);

  // zero f2..f4 (atomic-max targets) + g3,g2,g1 (split-K atomicAdd targets).
  hipMemsetAsync(f2, 0,
                 ((size_t)8 * (256 * 128 + 128 * 256 + 64 * 512) +
                  (size_t)8 * (128 * 512 + 256 * 256 + 512 * 128)) * 4, stream);

  fps4_kernel<256, 16><<<8, 256, 0, stream>>>(x, xyz, nrm, xyz4, 4096, 512, x1);
  knn20_kernel<<<8 * 512 / 4, 256, 0, stream>>>(x1, xyz4, nrm, W0, b0, f1);
  neighbors_kernel<<<1052, 256, 0, stream>>>(xyz, x1, nidx2, nidx3, nidx4,
                                             idx3_3, w3_3, idx3_2, w3_2,
                                             idx3_1, w3_1, idx3_0, w3_0);

  // ---- SA2: gather (40960 x 68) -> dense GEMM+maxpool (K=67, N=128) ----
  gather_sa_kernel<<<8 * 256 * 20 / 4, 256, 0, stream>>>(x1, f1, x1, nidx2, Abuf,
                                                         512, 512, 256, 512, 64, 68);
  {
    dim3 grid(2, 8 * 256 * 20 / 64);
    gemm_dsa_kernel<<<grid, 256, 0, stream>>>(Abuf, 68, W1, b1, f2,
                                              8 * 256 * 20, 128, 67);
  }
  // ---- SA3: gather (20480 x 132) -> dense GEMM+maxpool (K=131, N=256) ----
  gather_sa_kernel<<<8 * 128 * 20 / 4, 256, 0, stream>>>(x1, f2, x1, nidx3, Abuf,
                                                         256, 512, 128, 512, 128, 132);
  {
    dim3 grid(4, 8 * 128 * 20 / 64);
    gemm_dsa_kernel<<<grid, 256, 0, stream>>>(Abuf, 132, W2, b2, f3,
                                              8 * 128 * 20, 256, 131);
  }
  // ---- SA4: gather (10240 x 260) -> dense GEMM+maxpool (K=259, N=512) ----
  gather_sa_kernel<<<8 * 64 * 20 / 4, 256, 0, stream>>>(x1, f3, x1, nidx4, Abuf,
                                                        128, 512, 64, 512, 256, 260);
  {
    dim3 grid(8, 8 * 64 * 20 / 64);
    gemm_dsa_kernel<<<grid, 256, 0, stream>>>(Abuf, 260, W3, b3, f4,
                                              8 * 64 * 20, 512, 259);
  }

  // ---- FP3: interp -> dense A (1024x768); GEMM splitK x4 ----
  interp_kernel<<<8 * 128 / 4, 256, 0, stream>>>(f4, idx3_3, w3_3, f3, nullptr,
                                                 Abuf, 128, 64, 512, 256, 768);
  {
    dim3 grid(8, cdiv(8 * 128, 64), 4);
    gemm_dense_kernel<<<grid, 256, 0, stream>>>(Abuf, 768, 768,
                                                nullptr, nullptr, nullptr,
                                                F3, fb3, g3, 8 * 128, 512, 768,
                                                0, 1, 192, 0);
  }
  // ---- FP2: interp (g3 raw + fb3 finalize + skip f2) -> A (2048x640); splitK x4 ----
  interp_kernel<<<8 * 256 / 4, 256, 0, stream>>>(g3, idx3_2, w3_2, f2, fb3,
                                                 Abuf, 256, 128, 512, 128, 640);
  {
    dim3 grid(4, cdiv(8 * 256, 64), 4);
    gemm_dense_kernel<<<grid, 256, 0, stream>>>(Abuf, 640, 640,
                                                nullptr, nullptr, nullptr,
                                                F2, fb2, g2, 8 * 256, 256, 640,
                                                0, 1, 160, 0);
  }
  // ---- FP1: interp (g2 raw + fb2 + skip f1) -> A (4096x320); splitK x2 ----
  interp_kernel<<<8 * 512 / 4, 256, 0, stream>>>(g2, idx3_1, w3_1, f1, fb2,
                                                 Abuf, 512, 256, 256, 64, 320);
  {
    dim3 grid(2, cdiv(8 * 512, 64), 2);
    gemm_dense_kernel<<<grid, 256, 0, stream>>>(Abuf, 320, 320,
                                                nullptr, nullptr, nullptr,
                                                F1, fb1, g1, 8 * 512, 128, 320,
                                                0, 1, 160, 0);
  }
  // ---- FP0: interp (g1 raw + fb1, 128ch) -> A (32768x128); GEMM + tail K=150 ----
  interp_kernel<<<8 * 4096 / 4, 256, 0, stream>>>(g1, idx3_0, w3_0, nullptr, fb1,
                                                  Abuf, 4096, 512, 128, 0, 128);
  {
    dim3 grid(2, cdiv(8 * 4096, 64), 1);
    gemm_dense_kernel<<<grid, 256, 0, stream>>>(Abuf, 128, 128,
                                                cls, xyz, nrm,
                                                F0, fb0, g0, 8 * 4096, 128, 150,
                                                1, 0, 160, 4096);
  }

  // ---- seg head + fused transpose ----
  {
    dim3 grid(1, cdiv(8 * 4096, 64));
    gemm_seg_kernel<<<grid, 256, 0, stream>>>(g0, Wseg, bseg, out,
                                              out + (size_t)8 * 4096 * 50,
                                              8 * 4096, 50, 128);
  }
}